// Round 13
// baseline (159.146 us; speedup 1.0000x reference)
//
#include <hip/hip_runtime.h>
#include <math.h>

#define BN 2
#define HH 160
#define WW 160
#define CDATA 8
#define PS 10
#define STR 5
#define N1 31
#define N2 31
#define NSITE (N1*N2)
#define SITES (BN*NSITE)
#define SWIN 15
#define NOFF 225
#define KK 7
#define EDIM 800
#define NPIX 25600          // HH*WW
#define LP 40               // conv1/conv3 LDS pitch (ushorts)
#define LP2 72              // conv2 LDS pitch (64 k + 8 pad)
#define KP 480              // agg A k-pitch (= 15 dj * 32 j2-slots)
#define COLP 992            // ypT col pitch (31 j1 * 32 j2-slots)
#define GP 34               // gram LDS pitch (ushorts): 32 k + 2 pad
#define KSPLIT 5            // gram K-split (5 x 160)
#define GRAMBLKS (BN*N1*2*KSPLIT)   // 620
#define YNTBLKS ((SITES+3)/4)       // 481

typedef __attribute__((ext_vector_type(8))) short s8v;
typedef __attribute__((ext_vector_type(8))) unsigned short u8v;
typedef __attribute__((ext_vector_type(4))) unsigned short u4v;
typedef __attribute__((ext_vector_type(4))) float f4v;

__device__ __forceinline__ unsigned short f2bf(float f) {
    unsigned u = __float_as_uint(f);
    return (unsigned short)((u + 0x7FFFu + ((u >> 16) & 1u)) >> 16);
}
__device__ __forceinline__ float bf2f(unsigned short h) {
    return __uint_as_float(((unsigned)h) << 16);
}

// ---------- prep: w2 pack + w1 pack + w3 hi/lo pack (ypT moved into conv1 launch) ----------
__global__ __launch_bounds__(256) void prep_k(const float* __restrict__ ew2,
                                              const float* __restrict__ tw2,
                                              const float* __restrict__ ew1,
                                              const float* __restrict__ tw1,
                                              const float* __restrict__ ew3,
                                              const float* __restrict__ tw3,
                                              unsigned short* __restrict__ wp,
                                              unsigned short* __restrict__ wp1,
                                              unsigned short* __restrict__ wp3) {
    int blk = blockIdx.x;
    int t = threadIdx.x;
    if (blk < 288) {             // w2 pack [2][n=64][k=576], k=tap*64+c
        int idx = blk * 256 + t;
        int which = idx / (64 * 576); int r = idx % (64 * 576);
        int n = r / 576, k = r % 576;
        int p = k / 64, c = k % 64;
        const float* w = which ? tw2 : ew2;
        wp[idx] = f2bf(w[(n * 64 + c) * 9 + p]);
    } else if (blk < 336) {      // w1 pack [n=128][k=96], k=tap*8+c, taps>=9 zero
        int idx = (blk - 288) * 256 + t;
        if (idx < 128 * 96) {
            int n = idx / 96, k = idx % 96;
            int tap = k >> 3, c = k & 7;
            unsigned short v = 0;
            if (tap < 9) {
                const float* w = (n < 64) ? ew1 : tw1;
                v = f2bf(w[((n & 63) * 8 + c) * 9 + tap]);
            }
            wp1[idx] = v;
        }
    } else {                     // w3 pack [2][16][576]: hi/lo weight split in n
        int idx = (blk - 336) * 256 + t;
        if (idx < 2 * 16 * 576) {
            int which = idx / (16 * 576); int r = idx % (16 * 576);
            int n = r / 576, k = r % 576;
            int tap = k / 64, c = k % 64;
            float w = 0.f; bool lo = false;
            if (which == 0) { w = ew3[((n & 7) * 64 + c) * 9 + tap]; lo = (n >= 8); }
            else if (n < 2) { w = tw3[c * 9 + tap]; lo = (n == 1); }
            unsigned short hi = f2bf(w);
            wp3[idx] = lo ? f2bf(w - bf2f(hi)) : hi;
            if (which == 1 && n >= 2) wp3[idx] = 0;
        }
    }
}

// ---------- conv1 (blocks <800) + ypT build (blocks >=800), one launch ----------
__global__ __launch_bounds__(256) void conv1_ypt_k(const float* __restrict__ xf,
                                                   const float* __restrict__ xd,
                                                   const unsigned short* __restrict__ wp1,
                                                   const float* __restrict__ eb1,
                                                   const float* __restrict__ tb1,
                                                   unsigned short* __restrict__ h1,
                                                   unsigned short* __restrict__ ypT) {
    const int t = threadIdx.x;
    if (blockIdx.x >= 800) {     // ypT[b][e][j1*32+j2] bf16, zero at j2==31
        int row = blockIdx.x - 800;        // b*800 + e
        int b = row / 800, e = row % 800;
        int cd = e & 7, pp = e >> 3;
        int pi = pp / 10, pj = pp % 10;
        const float* src = xd + ((size_t)(b * 8 + cd) * HH + pi) * WW + pj;
        unsigned short* dst = ypT + (size_t)row * COLP;
        for (int it = 0; it < 4; ++it) {
            int col = it * 256 + t;
            if (col < COLP) {
                int j1 = col >> 5, j2 = col & 31;
                unsigned short v = 0;
                if (j2 < 31) v = f2bf(src[(j1 * 5) * WW + j2 * 5]);
                dst[col] = v;
            }
        }
        return;
    }
    __shared__ unsigned short Al[128 * LP];   // n x k32
    __shared__ unsigned short Bl[64 * LP];    // m x k32
    const int m0 = blockIdx.x * 64;
    const int wv = t >> 6, lane = t & 63;
    f4v acc[2][4];
    #pragma unroll
    for (int fj = 0; fj < 2; ++fj)
        #pragma unroll
        for (int fi = 0; fi < 4; ++fi) { f4v z = {0.f,0.f,0.f,0.f}; acc[fj][fi] = z; }
    const int mp = m0 + (t >> 2);
    const int b = mp / NPIX, rp = mp % NPIX;
    const int py = rp / WW, px = rp % WW;
    for (int ks = 0; ks < 3; ++ks) {
        int tap = ks * 4 + (t & 3);
        int dy = tap / 3 - 1, dx = tap % 3 - 1;
        int yy = py + dy, xx = px + dx;
        bool ok = (tap < 9) && yy >= 0 && yy < HH && xx >= 0 && xx < WW;
        u8v bv;
        #pragma unroll
        for (int c = 0; c < 8; ++c)
            bv[c] = ok ? f2bf(xf[((size_t)(b * 8 + c)) * NPIX + yy * WW + xx]) : 0;
        __syncthreads();
        *(u8v*)(Bl + (t >> 2) * LP + (t & 3) * 8) = bv;
        #pragma unroll
        for (int it = 0; it < 2; ++it) {
            int idx = t + it * 256;
            int row = idx >> 2, seg = idx & 3;
            *(u8v*)(Al + row * LP + seg * 8) = *(const u8v*)(wp1 + row * 96 + ks * 32 + seg * 8);
        }
        __syncthreads();
        s8v af[2], bf[4];
        #pragma unroll
        for (int fj = 0; fj < 2; ++fj)
            af[fj] = *(const s8v*)((const short*)Al + (wv * 32 + fj * 16 + (lane & 15)) * LP + (lane >> 4) * 8);
        #pragma unroll
        for (int fi = 0; fi < 4; ++fi)
            bf[fi] = *(const s8v*)((const short*)Bl + (fi * 16 + (lane & 15)) * LP + (lane >> 4) * 8);
        #pragma unroll
        for (int fj = 0; fj < 2; ++fj)
            #pragma unroll
            for (int fi = 0; fi < 4; ++fi)
                acc[fj][fi] = __builtin_amdgcn_mfma_f32_16x16x32_bf16(af[fj], bf[fi], acc[fj][fi], 0, 0, 0);
    }
    #pragma unroll
    for (int fj = 0; fj < 2; ++fj) {
        int nb = wv * 32 + fj * 16 + (lane >> 4) * 4;
        float bias4[4];
        #pragma unroll
        for (int c = 0; c < 4; ++c) {
            int n = nb + c;
            bias4[c] = (n < 64) ? eb1[n] : tb1[n - 64];
        }
        #pragma unroll
        for (int fi = 0; fi < 4; ++fi) {
            int mm = m0 + fi * 16 + (lane & 15);
            ushort4 o;
            o.x = f2bf(fmaxf(acc[fj][fi][0] + bias4[0], 0.f));
            o.y = f2bf(fmaxf(acc[fj][fi][1] + bias4[1], 0.f));
            o.z = f2bf(fmaxf(acc[fj][fi][2] + bias4[2], 0.f));
            o.w = f2bf(fmaxf(acc[fj][fi][3] + bias4[3], 0.f));
            *(ushort4*)(h1 + (size_t)mm * 128 + nb) = o;
        }
    }
}

// ---------- conv2: bf16 MFMA implicit GEMM, M=128 tile, K-step 64 (9 barrier-pairs) ----------
__global__ __launch_bounds__(256) void conv2_mfma_k(const unsigned short* __restrict__ h1,
                                                    const unsigned short* __restrict__ wp,
                                                    const float* __restrict__ eb2,
                                                    const float* __restrict__ tb2,
                                                    unsigned short* __restrict__ h2) {
    __shared__ unsigned short Al[64 * LP2];    // n=64 x k64
    __shared__ unsigned short Bl[128 * LP2];   // m=128 x k64
    const int t = threadIdx.x;
    const int which = blockIdx.y;
    const int m0 = blockIdx.x * 128;
    const int wv = t >> 6, lane = t & 63;
    f4v acc[4][2];   // [nf][mf]
    #pragma unroll
    for (int nf = 0; nf < 4; ++nf)
        #pragma unroll
        for (int mf = 0; mf < 2; ++mf) { f4v z = {0.f,0.f,0.f,0.f}; acc[nf][mf] = z; }
    const unsigned short* wb = wp + (size_t)which * 64 * 576;
    const int sm = t >> 2, sq = (t & 3) * 8;
    const int mp0 = m0 + sm;
    const int b0 = mp0 / NPIX, rp0 = mp0 % NPIX;
    const int py0 = rp0 / WW, px0 = rp0 % WW;
    const int mp1 = m0 + 64 + sm;
    const int b1_ = mp1 / NPIX, rp1 = mp1 % NPIX;
    const int py1 = rp1 / WW, px1 = rp1 % WW;
    for (int p = 0; p < 9; ++p) {
        const int dy = p / 3 - 1, dx = p % 3 - 1;
        s8v av[2], bv0[2], bv1[2];
        #pragma unroll
        for (int hh = 0; hh < 2; ++hh) {
            av[hh] = *(const s8v*)(wb + sm * 576 + p * 64 + hh * 32 + sq);
            #pragma unroll
            for (int j = 0; j < 8; j++) { bv0[hh][j] = 0; bv1[hh][j] = 0; }
        }
        int yy = py0 + dy, xx = px0 + dx;
        if (yy >= 0 && yy < HH && xx >= 0 && xx < WW) {
            const short* src = (const short*)h1 + ((size_t)b0 * NPIX + yy * WW + xx) * 128 + which * 64 + sq;
            bv0[0] = *(const s8v*)src; bv0[1] = *(const s8v*)(src + 32);
        }
        yy = py1 + dy; xx = px1 + dx;
        if (yy >= 0 && yy < HH && xx >= 0 && xx < WW) {
            const short* src = (const short*)h1 + ((size_t)b1_ * NPIX + yy * WW + xx) * 128 + which * 64 + sq;
            bv1[0] = *(const s8v*)src; bv1[1] = *(const s8v*)(src + 32);
        }
        __syncthreads();
        #pragma unroll
        for (int hh = 0; hh < 2; ++hh) {
            *(s8v*)((short*)Al + sm * LP2 + hh * 32 + sq) = av[hh];
            *(s8v*)((short*)Bl + sm * LP2 + hh * 32 + sq) = bv0[hh];
            *(s8v*)((short*)Bl + (64 + sm) * LP2 + hh * 32 + sq) = bv1[hh];
        }
        __syncthreads();
        #pragma unroll
        for (int kk = 0; kk < 2; ++kk) {
            s8v af[4], bf[2];
            #pragma unroll
            for (int nf = 0; nf < 4; ++nf)
                af[nf] = *(const s8v*)((const short*)Al + (nf * 16 + (lane & 15)) * LP2 + kk * 32 + (lane >> 4) * 8);
            #pragma unroll
            for (int mf = 0; mf < 2; ++mf)
                bf[mf] = *(const s8v*)((const short*)Bl + (wv * 32 + mf * 16 + (lane & 15)) * LP2 + kk * 32 + (lane >> 4) * 8);
            #pragma unroll
            for (int nf = 0; nf < 4; ++nf)
                #pragma unroll
                for (int mf = 0; mf < 2; ++mf)
                    acc[nf][mf] = __builtin_amdgcn_mfma_f32_16x16x32_bf16(af[nf], bf[mf], acc[nf][mf], 0, 0, 0);
        }
    }
    const float* bias = which ? tb2 : eb2;
    #pragma unroll
    for (int nf = 0; nf < 4; ++nf) {
        int nb = nf * 16 + (lane >> 4) * 4;
        f4v bv4 = *(const f4v*)(bias + nb);
        #pragma unroll
        for (int mf = 0; mf < 2; ++mf) {
            int mm = m0 + wv * 32 + mf * 16 + (lane & 15);
            ushort4 o;
            o.x = f2bf(fmaxf(acc[nf][mf][0] + bv4[0], 0.f));
            o.y = f2bf(fmaxf(acc[nf][mf][1] + bv4[1], 0.f));
            o.z = f2bf(fmaxf(acc[nf][mf][2] + bv4[2], 0.f));
            o.w = f2bf(fmaxf(acc[nf][mf][3] + bv4[3], 0.f));
            *(ushort4*)(h2 + ((size_t)which * 51200 + mm) * 64 + nb) = o;
        }
    }
}

// ---------- conv3: bf16 MFMA, N=16 weight hi/lo; emits xeH/xeL bf16 NHWC + splane + ltm ----------
__global__ __launch_bounds__(256) void conv3_mfma_k(const unsigned short* __restrict__ h2,
                                                    const unsigned short* __restrict__ wp3,
                                                    const float* __restrict__ eb3,
                                                    const float* __restrict__ tb3,
                                                    unsigned short* __restrict__ xeH,
                                                    unsigned short* __restrict__ xeL,
                                                    float* __restrict__ splane,
                                                    float* __restrict__ ltm) {
    __shared__ unsigned short Al[16 * LP];
    __shared__ unsigned short Bl[128 * LP];
    const int t = threadIdx.x;
    const int which = blockIdx.y;
    const int m0 = blockIdx.x * 128;
    const int wv = t >> 6, lane = t & 63;
    f4v acc[2];
    { f4v z = {0.f,0.f,0.f,0.f}; acc[0] = z; acc[1] = z; }
    const unsigned short* wb = wp3 + (size_t)which * 16 * 576;
    const int sm = t >> 2, sq = (t & 3) * 8;
    const int mp0 = m0 + sm;
    const int b0 = mp0 / NPIX, rp0 = mp0 % NPIX;
    const int py0 = rp0 / WW, px0 = rp0 % WW;
    const int mp1 = m0 + 64 + sm;
    const int b1_ = mp1 / NPIX, rp1 = mp1 % NPIX;
    const int py1 = rp1 / WW, px1 = rp1 % WW;
    for (int step = 0; step < 18; ++step) {
        const int p = step >> 1, ch = (step & 1) * 32;
        const int dy = p / 3 - 1, dx = p % 3 - 1;
        s8v av;
        if (t < 64) av = *(const s8v*)(wb + (t >> 2) * 576 + p * 64 + ch + (t & 3) * 8);
        s8v bv0, bv1;
        #pragma unroll
        for (int j = 0; j < 8; j++) { bv0[j] = 0; bv1[j] = 0; }
        int yy = py0 + dy, xx = px0 + dx;
        if (yy >= 0 && yy < HH && xx >= 0 && xx < WW)
            bv0 = *(const s8v*)((const short*)h2 + ((size_t)which * 51200 + (size_t)b0 * NPIX + yy * WW + xx) * 64 + ch + sq);
        yy = py1 + dy; xx = px1 + dx;
        if (yy >= 0 && yy < HH && xx >= 0 && xx < WW)
            bv1 = *(const s8v*)((const short*)h2 + ((size_t)which * 51200 + (size_t)b1_ * NPIX + yy * WW + xx) * 64 + ch + sq);
        __syncthreads();
        if (t < 64) *(s8v*)((short*)Al + (t >> 2) * LP + (t & 3) * 8) = av;
        *(s8v*)((short*)Bl + sm * LP + sq) = bv0;
        *(s8v*)((short*)Bl + (64 + sm) * LP + sq) = bv1;
        __syncthreads();
        s8v af = *(const s8v*)((const short*)Al + (lane & 15) * LP + (lane >> 4) * 8);
        #pragma unroll
        for (int mf = 0; mf < 2; ++mf) {
            s8v bf = *(const s8v*)((const short*)Bl + (wv * 32 + mf * 16 + (lane & 15)) * LP + (lane >> 4) * 8);
            acc[mf] = __builtin_amdgcn_mfma_f32_16x16x32_bf16(af, bf, acc[mf], 0, 0, 0);
        }
    }
    #pragma unroll
    for (int mf = 0; mf < 2; ++mf) {
        int mm = m0 + wv * 32 + mf * 16 + (lane & 15);
        if (which == 0) {
            f4v hilo;
            #pragma unroll
            for (int c = 0; c < 4; ++c)
                hilo[c] = acc[mf][c] + __shfl_xor(acc[mf][c], 32);   // n (hi) + n+8 (lo)
            if (lane < 32) {
                int nb = (lane >> 4) * 4;
                u4v hs, ls;
                float ss = 0.f;
                #pragma unroll
                for (int c = 0; c < 4; ++c) {
                    float v = hilo[c] + eb3[nb + c];
                    unsigned short h = f2bf(v);
                    hs[c] = h;
                    ls[c] = f2bf(v - bf2f(h));
                    ss += v * v;
                }
                *(u4v*)(xeH + (size_t)mm * 8 + nb) = hs;
                *(u4v*)(xeL + (size_t)mm * 8 + nb) = ls;
                ss += __shfl_xor(ss, 16);      // combine ch 0-3 with 4-7
                if (lane < 16) splane[mm] = ss;
            }
        } else {
            if ((lane >> 4) == 0)
                ltm[mm] = acc[mf][0] + acc[mf][1] + tb3[0];          // n0 hi + n1 lo
        }
    }
}

// ---------- gram (blocks <620) + ynt (blocks >=620), one launch ----------
__global__ __launch_bounds__(256) void gram_ynt_k(const unsigned short* __restrict__ xeH,
                                                  const unsigned short* __restrict__ xeL,
                                                  const float* __restrict__ splane,
                                                  const float* __restrict__ ltm,
                                                  float* __restrict__ dotsC,
                                                  float* __restrict__ yn,
                                                  float* __restrict__ tempv) {
    if (blockIdx.x >= GRAMBLKS) {    // ynt path: wave per site
        int wv = threadIdx.x >> 6, lane = threadIdx.x & 63;
        int wid = (blockIdx.x - GRAMBLKS) * 4 + wv;
        if (wid >= SITES) return;
        int b = wid / NSITE; int ij = wid % NSITE;
        int i1 = ij / N2, i2 = ij % N2;
        float s1 = 0.f, s2 = 0.f;
        for (int p = lane; p < 100; p += 64) {
            int rr = p / 10, q = p % 10;
            int idx = b * NPIX + (i1 * STR + rr) * WW + i2 * STR + q;
            s1 += splane[idx];
            s2 += ltm[idx];
        }
        #pragma unroll
        for (int o = 32; o; o >>= 1) { s1 += __shfl_xor(s1, o); s2 += __shfl_xor(s2, o); }
        if (lane == 0) {
            yn[wid] = s1;
            tempv[wid] = expf(s2 * (1.f / 100.f));
        }
        return;
    }
    __shared__ unsigned short AsH[32 * GP], AsL[32 * GP];
    __shared__ unsigned short BsH[256 * GP], BsL[256 * GP];
    int blk = blockIdx.x;                  // ((b*31+i1)*2+nh)*KSPLIT + kc
    int kc = blk % KSPLIT; int r = blk / KSPLIT;
    int nh = r & 1; r >>= 1;
    int b = r / N1, i1 = r % N1;
    int b1 = min(max(i1 - 7, 0), 16);
    int t = threadIdx.x;
    int wv = t >> 6, lane = t & 63;
    f4v acc[2][4];
    #pragma unroll
    for (int mt = 0; mt < 2; ++mt)
        #pragma unroll
        for (int nt = 0; nt < 4; ++nt) { f4v z = {0.f,0.f,0.f,0.f}; acc[mt][nt] = z; }
    const size_t pbase = (size_t)b * NPIX;
    for (int ks = kc * 5; ks < kc * 5 + 5; ++ks) {
        __syncthreads();
        {   // stage A: rows = i2 (0..31), pixel p = ks*4+seg
            int idx = t & 127;
            int row = idx >> 2, seg = idx & 3;
            int p = ks * 4 + seg;
            int rr = p / 10, q = p - rr * 10;
            u8v v;
            #pragma unroll
            for (int u = 0; u < 8; ++u) v[u] = 0;
            if (row < 31) {
                size_t a = (pbase + (size_t)(i1 * STR + rr) * WW + row * STR + q) * 8;
                v = *(const u8v*)((t < 128 ? xeH : xeL) + a);
            }
            *(u8v*)((t < 128 ? AsH : AsL) + row * GP + seg * 8) = v;
        }
        #pragma unroll
        for (int rep = 0; rep < 8; ++rep) {   // stage B: rows = dj,j2
            int idx = t + rep * 256;
            int isH = idx < 1024;
            int id2 = idx & 1023;
            int row = id2 >> 2, seg = id2 & 3;
            int dj = nh * 8 + (row >> 5), j2 = row & 31;
            int p = ks * 4 + seg;
            int rr = p / 10, q = p - rr * 10;
            u8v v;
            #pragma unroll
            for (int u = 0; u < 8; ++u) v[u] = 0;
            if (dj < 15 && j2 < 31) {
                size_t a = (pbase + (size_t)((b1 + dj) * STR + rr) * WW + j2 * STR + q) * 8;
                v = *(const u8v*)((isH ? xeH : xeL) + a);
            }
            *(u8v*)((isH ? BsH : BsL) + row * GP + seg * 8) = v;
        }
        __syncthreads();
        s8v afH[2], afL[2], bfH[4], bfL[4];
        #pragma unroll
        for (int mt = 0; mt < 2; ++mt) {
            int ar = mt * 16 + (lane & 15);
            afH[mt] = *(const s8v*)((const short*)AsH + ar * GP + (lane >> 4) * 8);
            afL[mt] = *(const s8v*)((const short*)AsL + ar * GP + (lane >> 4) * 8);
        }
        #pragma unroll
        for (int nt = 0; nt < 4; ++nt) {
            int br = wv * 64 + nt * 16 + (lane & 15);
            bfH[nt] = *(const s8v*)((const short*)BsH + br * GP + (lane >> 4) * 8);
            bfL[nt] = *(const s8v*)((const short*)BsL + br * GP + (lane >> 4) * 8);
        }
        #pragma unroll
        for (int mt = 0; mt < 2; ++mt)
            #pragma unroll
            for (int nt = 0; nt < 4; ++nt) {
                acc[mt][nt] = __builtin_amdgcn_mfma_f32_16x16x32_bf16(afH[mt], bfH[nt], acc[mt][nt], 0, 0, 0);
                acc[mt][nt] = __builtin_amdgcn_mfma_f32_16x16x32_bf16(afH[mt], bfL[nt], acc[mt][nt], 0, 0, 0);
                acc[mt][nt] = __builtin_amdgcn_mfma_f32_16x16x32_bf16(afL[mt], bfH[nt], acc[mt][nt], 0, 0, 0);
            }
    }
    float* dk = dotsC + (size_t)kc * SITES * NOFF;
    #pragma unroll
    for (int mt = 0; mt < 2; ++mt) {
        int i2b = mt * 16 + (lane >> 4) * 4;
        #pragma unroll
        for (int nt = 0; nt < 4; ++nt) {
            int n = wv * 64 + nt * 16 + (lane & 15);
            int dj = nh * 8 + (n >> 5), j2 = n & 31;
            if (dj >= 15 || j2 >= 31) continue;
            #pragma unroll
            for (int c = 0; c < 4; ++c) {
                int i2 = i2b + c;
                if (i2 >= 31) continue;
                int b2 = min(max(i2 - 7, 0), 16);
                int dc = j2 - b2;
                if (dc < 0 || dc >= SWIN) continue;
                size_t site = (size_t)((b * N1 + i1) * N2 + i2);
                dk[site * NOFF + dj * SWIN + dc] = acc[mt][nt][c];
            }
        }
    }
}

// ---------- fused softmax + A-build: wave per site writes Aglob rows directly ----------
__global__ __launch_bounds__(256) void softmax_awrite_k(const float* __restrict__ dotsC,
                                                        const float* __restrict__ yn,
                                                        const float* __restrict__ tempv,
                                                        unsigned short* __restrict__ Aglob) {
    __shared__ float sw[4][228];
    int wv = threadIdx.x >> 6, lane = threadIdx.x & 63;
    int wid = blockIdx.x * 4 + wv;
    bool active = (wid < SITES);
    int wids = active ? wid : (SITES - 1);
    int b = wids / NSITE; int ij = wids % NSITE;
    int i1 = ij / N2, i2 = ij % N2;
    int b1 = min(max(i1 - 7, 0), 16);
    int b2 = min(max(i2 - 7, 0), 16);
    int pglob = i2 >> 1, s = i2 & 1;
    unsigned short* Abase = Aglob + (size_t)((b * N1 + i1) * 256) * KP;
    float yns = yn[wids];
    float tvi = 1.f / tempv[wids];
    float lg[4];
    #pragma unroll
    for (int r = 0; r < 4; ++r) {
        int t = lane + 64 * r;
        lg[r] = -1e9f;
        if (t < NOFF) {
            float dot = 0.f;
            #pragma unroll
            for (int kc = 0; kc < KSPLIT; ++kc)
                dot += dotsC[((size_t)kc * SITES + wids) * NOFF + t];
            int dj = t / SWIN, dc = t % SWIN;
            int j1 = b1 + dj, j2 = b2 + dc;
            float xn = yn[(b * N1 + j1) * N2 + j2];
            float d = yns + xn - 2.f * dot;
            lg[r] = -d * tvi;
            if (j1 == i1 && j2 == i2) lg[r] = -1e9f;
        }
    }
    for (int k = 0; k < KK; ++k) {
        float m = fmaxf(fmaxf(lg[0], lg[1]), fmaxf(lg[2], lg[3]));
        #pragma unroll
        for (int o = 32; o; o >>= 1) m = fmaxf(m, __shfl_xor(m, o));
        float ex[4]; float ssum = 0.f;
        #pragma unroll
        for (int r = 0; r < 4; ++r) { ex[r] = __expf(lg[r] - m); ssum += ex[r]; }
        #pragma unroll
        for (int o = 32; o; o >>= 1) ssum += __shfl_xor(ssum, o);
        float inv = 1.f / ssum;
        #pragma unroll
        for (int r = 0; r < 4; ++r) {
            float wgt = ex[r] * inv;
            int t = lane + 64 * r;
            if (t < NOFF) sw[wv][t] = wgt;
            lg[r] += log1pf(-fminf(wgt, 1.f - 1e-6f));
        }
        __syncthreads();
        if (active && lane < 60) {
            u8v o;
            #pragma unroll
            for (int u = 0; u < 8; ++u) {
                int n = lane * 8 + u;
                int dj = n >> 5, j2 = n & 31;
                int dc = j2 - b2;
                o[u] = (j2 < 31 && dc >= 0 && dc < SWIN) ? f2bf(sw[wv][dj * SWIN + dc]) : (unsigned short)0;
            }
            int m_ = 16 * pglob + k + 7 * s;
            *(u8v*)(Abase + (size_t)m_ * KP + lane * 8) = o;
        }
        __syncthreads();
    }
    if (active && s == 0 && lane < 60) {
        u8v z;
        #pragma unroll
        for (int u = 0; u < 8; ++u) z[u] = 0;
        *(u8v*)(Abase + (size_t)(16 * pglob + 14) * KP + lane * 8) = z;
        *(u8v*)(Abase + (size_t)(16 * pglob + 15) * KP + lane * 8) = z;
        if (i2 == 30) {
            #pragma unroll
            for (int sl = 7; sl < 14; ++sl)
                *(u8v*)(Abase + (size_t)(16 * 15 + sl) * KP + lane * 8) = z;
        }
    }
}

// ---------- agg GEMM: per (b,i1): C[256 m][800 e] = A[256x480] * ypT-slice^T ----------
__global__ __launch_bounds__(256) void agg_gemm_k(const unsigned short* __restrict__ Aglob,
                                                  const unsigned short* __restrict__ ypT,
                                                  unsigned short* __restrict__ zbuf) {
    __shared__ unsigned short As[128 * 40];
    __shared__ unsigned short Bs[160 * 40];
    int blk = blockIdx.x;                     // b*310 + i1*10 + mh*5 + nc
    int b = blk / 310; int r = blk % 310;
    int i1 = r / 10; int r2 = r % 10;
    int mh = r2 / 5, nc = r2 % 5;
    int b1 = min(max(i1 - 7, 0), 16);
    int t = threadIdx.x;
    int wv = t >> 6, lane = t & 63;
    int wm = (wv & 1) * 64, we = (wv >> 1) * 80;
    const unsigned short* Ab = Aglob + ((size_t)(b * N1 + i1) * 256 + mh * 128) * KP;
    const unsigned short* Bb = ypT + ((size_t)b * 800 + nc * 160) * COLP + b1 * 32;
    f4v accr[4][5];
    #pragma unroll
    for (int mt = 0; mt < 4; ++mt)
        #pragma unroll
        for (int et = 0; et < 5; ++et) { f4v z = {0.f,0.f,0.f,0.f}; accr[mt][et] = z; }
    for (int ks = 0; ks < 15; ++ks) {
        __syncthreads();
        #pragma unroll
        for (int it = 0; it < 2; ++it) {
            int idx = t + it * 256;
            int row = idx >> 2, seg = idx & 3;
            *(u8v*)(As + row * 40 + seg * 8) = *(const u8v*)(Ab + (size_t)row * KP + ks * 32 + seg * 8);
        }
        #pragma unroll
        for (int it = 0; it < 3; ++it) {
            int idx = t + it * 256;
            if (idx < 640) {
                int row = idx >> 2, seg = idx & 3;
                *(u8v*)(Bs + row * 40 + seg * 8) = *(const u8v*)(Bb + (size_t)row * COLP + ks * 32 + seg * 8);
            }
        }
        __syncthreads();
        s8v af[4], bf[5];
        #pragma unroll
        for (int mt = 0; mt < 4; ++mt)
            af[mt] = *(const s8v*)((const short*)As + (wm + mt * 16 + (lane & 15)) * 40 + (lane >> 4) * 8);
        #pragma unroll
        for (int et = 0; et < 5; ++et)
            bf[et] = *(const s8v*)((const short*)Bs + (we + et * 16 + (lane & 15)) * 40 + (lane >> 4) * 8);
        #pragma unroll
        for (int mt = 0; mt < 4; ++mt)
            #pragma unroll
            for (int et = 0; et < 5; ++et)
                accr[mt][et] = __builtin_amdgcn_mfma_f32_16x16x32_bf16(af[mt], bf[et], accr[mt][et], 0, 0, 0);
    }
    unsigned short* zb = zbuf + ((size_t)(b * N1 + i1) * 256 + mh * 128) * 800 + nc * 160;
    #pragma unroll
    for (int mt = 0; mt < 4; ++mt) {
        int mrow = wm + mt * 16 + (lane >> 4) * 4;
        #pragma unroll
        for (int et = 0; et < 5; ++et) {
            int ecol = we + et * 16 + (lane & 15);
            #pragma unroll
            for (int c = 0; c < 4; ++c)
                zb[(size_t)(mrow + c) * 800 + ecol] = f2bf(accr[mt][et][c]);
        }
    }
}

// ---------- finalize: thread per (b,pixel), all 64 channels ----------
__global__ __launch_bounds__(256) void finalize_k(const unsigned short* __restrict__ zbuf,
                                                  const float* __restrict__ xd,
                                                  float* __restrict__ out) {
    int pid = blockIdx.x * 256 + threadIdx.x;      // b*NPIX + pix
    if (pid >= BN * NPIX) return;
    int b = pid / NPIX, pix = pid % NPIX;
    int h = pix / WW, w_ = pix % WW;
    int lo1 = max(0, (h - 5) / 5),  hi1 = min(30, h / 5);
    int lo2 = max(0, (w_ - 5) / 5), hi2 = min(30, w_ / 5);
    float cntinv = 1.f / (float)((hi1 - lo1 + 1) * (hi2 - lo2 + 1));
    float xv[8];
    #pragma unroll
    for (int cd = 0; cd < 8; ++cd) {
        xv[cd] = xd[((size_t)(b * 8 + cd)) * NPIX + pix];
        out[((size_t)(b * 64 + cd)) * NPIX + pix] = xv[cd];
    }
    for (int k = 0; k < KK; ++k) {
        float s[8];
        #pragma unroll
        for (int cd = 0; cd < 8; ++cd) s[cd] = 0.f;
        for (int i1 = lo1; i1 <= hi1; ++i1) {
            int pi = h - 5 * i1;
            for (int i2 = lo2; i2 <= hi2; ++i2) {
                int pj = w_ - 5 * i2;
                int m = 16 * (i2 >> 1) + k + 7 * (i2 & 1);
                const unsigned short* zp = zbuf + ((size_t)(b * N1 + i1) * 256 + m) * 800 + (pi * 10 + pj) * 8;
                u8v zv = *(const u8v*)zp;
                #pragma unroll
                for (int cd = 0; cd < 8; ++cd) s[cd] += bf2f(zv[cd]);
            }
        }
        #pragma unroll
        for (int cd = 0; cd < 8; ++cd)
            out[((size_t)(b * 64 + (k + 1) * 8 + cd)) * NPIX + pix] = s[cd] * cntinv - xv[cd];
    }
}

extern "C" void kernel_launch(void* const* d_in, const int* in_sizes, int n_in,
                              void* d_out, int out_size, void* d_ws, size_t ws_size,
                              hipStream_t stream) {
    (void)in_sizes; (void)n_in; (void)out_size; (void)ws_size;
    const float* x_data = (const float*)d_in[0];
    const float* x_faet = (const float*)d_in[1];
    const float* ew1 = (const float*)d_in[2];  const float* eb1 = (const float*)d_in[3];
    const float* ew2 = (const float*)d_in[4];  const float* eb2 = (const float*)d_in[5];
    const float* ew3 = (const float*)d_in[6];  const float* eb3 = (const float*)d_in[7];
    const float* tw1 = (const float*)d_in[8];  const float* tb1 = (const float*)d_in[9];
    const float* tw2 = (const float*)d_in[10]; const float* tb2 = (const float*)d_in[11];
    const float* tw3 = (const float*)d_in[12]; const float* tb3 = (const float*)d_in[13];
    float* out = (float*)d_out;

    // workspace layout (bytes), total 44.8 MB (same as R11):
    char* base = (char*)d_ws;
    unsigned short* h1 = (unsigned short*)(base);
    unsigned short* h2 = (unsigned short*)(base + 13107200);
    unsigned short* wp1 = (unsigned short*)(base + 13107200);   // dead before conv2 writes h2
    unsigned short* wp = (unsigned short*)(base + 26214400);
    float* yn    = (float*)(base + 26361856);
    float* tempv = (float*)(base + 26370048);
    unsigned short* ypT = (unsigned short*)(base + 26378240);
    unsigned short* xeH = (unsigned short*)(base + 29552640);
    unsigned short* xeL = (unsigned short*)(base + 30371840);
    float* ltm    = (float*)(base + 31191040);
    float* splane = (float*)(base + 31395840);
    unsigned short* wp3 = (unsigned short*)(base + 37546240);
    unsigned short* Aglob = (unsigned short*)(base + 29552640);
    float* dotsC = (float*)h2;
    unsigned short* zbuf = (unsigned short*)base;

    prep_k<<<408, 256, 0, stream>>>(ew2, tw2, ew1, tw1, ew3, tw3, wp, wp1, wp3);
    conv1_ypt_k<<<800 + 1600, 256, 0, stream>>>(x_faet, x_data, wp1, eb1, tb1, h1, ypT);
    conv2_mfma_k<<<dim3(400, 2), 256, 0, stream>>>(h1, wp, eb2, tb2, h2);
    conv3_mfma_k<<<dim3(400, 2), 256, 0, stream>>>(h2, wp3, eb3, tb3, xeH, xeL, splane, ltm);

    gram_ynt_k<<<GRAMBLKS + YNTBLKS, 256, 0, stream>>>(xeH, xeL, splane, ltm, dotsC, yn, tempv);
    softmax_awrite_k<<<YNTBLKS, 256, 0, stream>>>(dotsC, yn, tempv, Aglob);

    agg_gemm_k<<<BN * 310, 256, 0, stream>>>(Aglob, ypT, zbuf);
    finalize_k<<<(BN * NPIX + 255) / 256, 256, 0, stream>>>(zbuf, x_data, out);
}

// Round 14
// 159.004 us; speedup vs baseline: 1.0009x; 1.0009x over previous
//
#include <hip/hip_runtime.h>
#include <math.h>

#define BN 2
#define HH 160
#define WW 160
#define CDATA 8
#define PS 10
#define STR 5
#define N1 31
#define N2 31
#define NSITE (N1*N2)
#define SITES (BN*NSITE)
#define SWIN 15
#define NOFF 225
#define KK 7
#define EDIM 800
#define NPIX 25600          // HH*WW
#define LP 40               // conv1/conv3 LDS pitch (ushorts)
#define LP2 72              // conv2 LDS pitch (64 k + 8 pad)
#define KP 480              // agg A k-pitch (= 15 dj * 32 j2-slots)
#define COLP 992            // ypT col pitch (31 j1 * 32 j2-slots)
#define GP 34               // gram LDS pitch (ushorts): 32 k + 2 pad
#define KSPLIT 5            // gram K-split (5 x 160)
#define GRAMBLKS (BN*N1*2*KSPLIT)   // 620
#define YNTBLKS ((SITES+3)/4)       // 481

typedef __attribute__((ext_vector_type(8))) short s8v;
typedef __attribute__((ext_vector_type(8))) unsigned short u8v;
typedef __attribute__((ext_vector_type(4))) unsigned short u4v;
typedef __attribute__((ext_vector_type(4))) float f4v;

__device__ __forceinline__ unsigned short f2bf(float f) {
    unsigned u = __float_as_uint(f);
    return (unsigned short)((u + 0x7FFFu + ((u >> 16) & 1u)) >> 16);
}
__device__ __forceinline__ float bf2f(unsigned short h) {
    return __uint_as_float(((unsigned)h) << 16);
}

// ---------- prep: w2 pack + w1 pack + w3 hi/lo pack (ypT moved into conv1 launch) ----------
__global__ __launch_bounds__(256) void prep_k(const float* __restrict__ ew2,
                                              const float* __restrict__ tw2,
                                              const float* __restrict__ ew1,
                                              const float* __restrict__ tw1,
                                              const float* __restrict__ ew3,
                                              const float* __restrict__ tw3,
                                              unsigned short* __restrict__ wp,
                                              unsigned short* __restrict__ wp1,
                                              unsigned short* __restrict__ wp3) {
    int blk = blockIdx.x;
    int t = threadIdx.x;
    if (blk < 288) {             // w2 pack [2][n=64][k=576], k=tap*64+c
        int idx = blk * 256 + t;
        int which = idx / (64 * 576); int r = idx % (64 * 576);
        int n = r / 576, k = r % 576;
        int p = k / 64, c = k % 64;
        const float* w = which ? tw2 : ew2;
        wp[idx] = f2bf(w[(n * 64 + c) * 9 + p]);
    } else if (blk < 336) {      // w1 pack [n=128][k=96], k=tap*8+c, taps>=9 zero
        int idx = (blk - 288) * 256 + t;
        if (idx < 128 * 96) {
            int n = idx / 96, k = idx % 96;
            int tap = k >> 3, c = k & 7;
            unsigned short v = 0;
            if (tap < 9) {
                const float* w = (n < 64) ? ew1 : tw1;
                v = f2bf(w[((n & 63) * 8 + c) * 9 + tap]);
            }
            wp1[idx] = v;
        }
    } else {                     // w3 pack [2][16][576]: hi/lo weight split in n
        int idx = (blk - 336) * 256 + t;
        if (idx < 2 * 16 * 576) {
            int which = idx / (16 * 576); int r = idx % (16 * 576);
            int n = r / 576, k = r % 576;
            int tap = k / 64, c = k % 64;
            float w = 0.f; bool lo = false;
            if (which == 0) { w = ew3[((n & 7) * 64 + c) * 9 + tap]; lo = (n >= 8); }
            else if (n < 2) { w = tw3[c * 9 + tap]; lo = (n == 1); }
            unsigned short hi = f2bf(w);
            wp3[idx] = lo ? f2bf(w - bf2f(hi)) : hi;
            if (which == 1 && n >= 2) wp3[idx] = 0;
        }
    }
}

// ---------- conv1 (blocks <800) + ypT build (blocks >=800), one launch ----------
__global__ __launch_bounds__(256) void conv1_ypt_k(const float* __restrict__ xf,
                                                   const float* __restrict__ xd,
                                                   const unsigned short* __restrict__ wp1,
                                                   const float* __restrict__ eb1,
                                                   const float* __restrict__ tb1,
                                                   unsigned short* __restrict__ h1,
                                                   unsigned short* __restrict__ ypT) {
    const int t = threadIdx.x;
    if (blockIdx.x >= 800) {     // ypT[b][e][j1*32+j2] bf16, zero at j2==31
        int row = blockIdx.x - 800;        // b*800 + e
        int b = row / 800, e = row % 800;
        int cd = e & 7, pp = e >> 3;
        int pi = pp / 10, pj = pp % 10;
        const float* src = xd + ((size_t)(b * 8 + cd) * HH + pi) * WW + pj;
        unsigned short* dst = ypT + (size_t)row * COLP;
        for (int it = 0; it < 4; ++it) {
            int col = it * 256 + t;
            if (col < COLP) {
                int j1 = col >> 5, j2 = col & 31;
                unsigned short v = 0;
                if (j2 < 31) v = f2bf(src[(j1 * 5) * WW + j2 * 5]);
                dst[col] = v;
            }
        }
        return;
    }
    __shared__ unsigned short Al[128 * LP];   // n x k32
    __shared__ unsigned short Bl[64 * LP];    // m x k32
    const int m0 = blockIdx.x * 64;
    const int wv = t >> 6, lane = t & 63;
    f4v acc[2][4];
    #pragma unroll
    for (int fj = 0; fj < 2; ++fj)
        #pragma unroll
        for (int fi = 0; fi < 4; ++fi) { f4v z = {0.f,0.f,0.f,0.f}; acc[fj][fi] = z; }
    const int mp = m0 + (t >> 2);
    const int b = mp / NPIX, rp = mp % NPIX;
    const int py = rp / WW, px = rp % WW;
    for (int ks = 0; ks < 3; ++ks) {
        int tap = ks * 4 + (t & 3);
        int dy = tap / 3 - 1, dx = tap % 3 - 1;
        int yy = py + dy, xx = px + dx;
        bool ok = (tap < 9) && yy >= 0 && yy < HH && xx >= 0 && xx < WW;
        u8v bv;
        #pragma unroll
        for (int c = 0; c < 8; ++c)
            bv[c] = ok ? f2bf(xf[((size_t)(b * 8 + c)) * NPIX + yy * WW + xx]) : 0;
        __syncthreads();
        *(u8v*)(Bl + (t >> 2) * LP + (t & 3) * 8) = bv;
        #pragma unroll
        for (int it = 0; it < 2; ++it) {
            int idx = t + it * 256;
            int row = idx >> 2, seg = idx & 3;
            *(u8v*)(Al + row * LP + seg * 8) = *(const u8v*)(wp1 + row * 96 + ks * 32 + seg * 8);
        }
        __syncthreads();
        s8v af[2], bf[4];
        #pragma unroll
        for (int fj = 0; fj < 2; ++fj)
            af[fj] = *(const s8v*)((const short*)Al + (wv * 32 + fj * 16 + (lane & 15)) * LP + (lane >> 4) * 8);
        #pragma unroll
        for (int fi = 0; fi < 4; ++fi)
            bf[fi] = *(const s8v*)((const short*)Bl + (fi * 16 + (lane & 15)) * LP + (lane >> 4) * 8);
        #pragma unroll
        for (int fj = 0; fj < 2; ++fj)
            #pragma unroll
            for (int fi = 0; fi < 4; ++fi)
                acc[fj][fi] = __builtin_amdgcn_mfma_f32_16x16x32_bf16(af[fj], bf[fi], acc[fj][fi], 0, 0, 0);
    }
    #pragma unroll
    for (int fj = 0; fj < 2; ++fj) {
        int nb = wv * 32 + fj * 16 + (lane >> 4) * 4;
        float bias4[4];
        #pragma unroll
        for (int c = 0; c < 4; ++c) {
            int n = nb + c;
            bias4[c] = (n < 64) ? eb1[n] : tb1[n - 64];
        }
        #pragma unroll
        for (int fi = 0; fi < 4; ++fi) {
            int mm = m0 + fi * 16 + (lane & 15);
            ushort4 o;
            o.x = f2bf(fmaxf(acc[fj][fi][0] + bias4[0], 0.f));
            o.y = f2bf(fmaxf(acc[fj][fi][1] + bias4[1], 0.f));
            o.z = f2bf(fmaxf(acc[fj][fi][2] + bias4[2], 0.f));
            o.w = f2bf(fmaxf(acc[fj][fi][3] + bias4[3], 0.f));
            *(ushort4*)(h1 + (size_t)mm * 128 + nb) = o;
        }
    }
}

// ---------- conv2: bf16 MFMA implicit GEMM, M=128 tile, K-step 64 (9 barrier-pairs) ----------
__global__ __launch_bounds__(256) void conv2_mfma_k(const unsigned short* __restrict__ h1,
                                                    const unsigned short* __restrict__ wp,
                                                    const float* __restrict__ eb2,
                                                    const float* __restrict__ tb2,
                                                    unsigned short* __restrict__ h2) {
    __shared__ unsigned short Al[64 * LP2];    // n=64 x k64
    __shared__ unsigned short Bl[128 * LP2];   // m=128 x k64
    const int t = threadIdx.x;
    const int which = blockIdx.y;
    const int m0 = blockIdx.x * 128;
    const int wv = t >> 6, lane = t & 63;
    f4v acc[4][2];   // [nf][mf]
    #pragma unroll
    for (int nf = 0; nf < 4; ++nf)
        #pragma unroll
        for (int mf = 0; mf < 2; ++mf) { f4v z = {0.f,0.f,0.f,0.f}; acc[nf][mf] = z; }
    const unsigned short* wb = wp + (size_t)which * 64 * 576;
    const int sm = t >> 2, sq = (t & 3) * 8;
    const int mp0 = m0 + sm;
    const int b0 = mp0 / NPIX, rp0 = mp0 % NPIX;
    const int py0 = rp0 / WW, px0 = rp0 % WW;
    const int mp1 = m0 + 64 + sm;
    const int b1_ = mp1 / NPIX, rp1 = mp1 % NPIX;
    const int py1 = rp1 / WW, px1 = rp1 % WW;
    for (int p = 0; p < 9; ++p) {
        const int dy = p / 3 - 1, dx = p % 3 - 1;
        s8v av[2], bv0[2], bv1[2];
        #pragma unroll
        for (int hh = 0; hh < 2; ++hh) {
            av[hh] = *(const s8v*)(wb + sm * 576 + p * 64 + hh * 32 + sq);
            #pragma unroll
            for (int j = 0; j < 8; j++) { bv0[hh][j] = 0; bv1[hh][j] = 0; }
        }
        int yy = py0 + dy, xx = px0 + dx;
        if (yy >= 0 && yy < HH && xx >= 0 && xx < WW) {
            const short* src = (const short*)h1 + ((size_t)b0 * NPIX + yy * WW + xx) * 128 + which * 64 + sq;
            bv0[0] = *(const s8v*)src; bv0[1] = *(const s8v*)(src + 32);
        }
        yy = py1 + dy; xx = px1 + dx;
        if (yy >= 0 && yy < HH && xx >= 0 && xx < WW) {
            const short* src = (const short*)h1 + ((size_t)b1_ * NPIX + yy * WW + xx) * 128 + which * 64 + sq;
            bv1[0] = *(const s8v*)src; bv1[1] = *(const s8v*)(src + 32);
        }
        __syncthreads();
        #pragma unroll
        for (int hh = 0; hh < 2; ++hh) {
            *(s8v*)((short*)Al + sm * LP2 + hh * 32 + sq) = av[hh];
            *(s8v*)((short*)Bl + sm * LP2 + hh * 32 + sq) = bv0[hh];
            *(s8v*)((short*)Bl + (64 + sm) * LP2 + hh * 32 + sq) = bv1[hh];
        }
        __syncthreads();
        #pragma unroll
        for (int kk = 0; kk < 2; ++kk) {
            s8v af[4], bf[2];
            #pragma unroll
            for (int nf = 0; nf < 4; ++nf)
                af[nf] = *(const s8v*)((const short*)Al + (nf * 16 + (lane & 15)) * LP2 + kk * 32 + (lane >> 4) * 8);
            #pragma unroll
            for (int mf = 0; mf < 2; ++mf)
                bf[mf] = *(const s8v*)((const short*)Bl + (wv * 32 + mf * 16 + (lane & 15)) * LP2 + kk * 32 + (lane >> 4) * 8);
            #pragma unroll
            for (int nf = 0; nf < 4; ++nf)
                #pragma unroll
                for (int mf = 0; mf < 2; ++mf)
                    acc[nf][mf] = __builtin_amdgcn_mfma_f32_16x16x32_bf16(af[nf], bf[mf], acc[nf][mf], 0, 0, 0);
        }
    }
    const float* bias = which ? tb2 : eb2;
    #pragma unroll
    for (int nf = 0; nf < 4; ++nf) {
        int nb = nf * 16 + (lane >> 4) * 4;
        f4v bv4 = *(const f4v*)(bias + nb);
        #pragma unroll
        for (int mf = 0; mf < 2; ++mf) {
            int mm = m0 + wv * 32 + mf * 16 + (lane & 15);
            ushort4 o;
            o.x = f2bf(fmaxf(acc[nf][mf][0] + bv4[0], 0.f));
            o.y = f2bf(fmaxf(acc[nf][mf][1] + bv4[1], 0.f));
            o.z = f2bf(fmaxf(acc[nf][mf][2] + bv4[2], 0.f));
            o.w = f2bf(fmaxf(acc[nf][mf][3] + bv4[3], 0.f));
            *(ushort4*)(h2 + ((size_t)which * 51200 + mm) * 64 + nb) = o;
        }
    }
}

// ---------- conv3: bf16 MFMA, N=16 weight hi/lo; emits xeH/xeL bf16 NHWC + splane + ltm ----------
__global__ __launch_bounds__(256) void conv3_mfma_k(const unsigned short* __restrict__ h2,
                                                    const unsigned short* __restrict__ wp3,
                                                    const float* __restrict__ eb3,
                                                    const float* __restrict__ tb3,
                                                    unsigned short* __restrict__ xeH,
                                                    unsigned short* __restrict__ xeL,
                                                    float* __restrict__ splane,
                                                    float* __restrict__ ltm) {
    __shared__ unsigned short Al[16 * LP];
    __shared__ unsigned short Bl[128 * LP];
    const int t = threadIdx.x;
    const int which = blockIdx.y;
    const int m0 = blockIdx.x * 128;
    const int wv = t >> 6, lane = t & 63;
    f4v acc[2];
    { f4v z = {0.f,0.f,0.f,0.f}; acc[0] = z; acc[1] = z; }
    const unsigned short* wb = wp3 + (size_t)which * 16 * 576;
    const int sm = t >> 2, sq = (t & 3) * 8;
    const int mp0 = m0 + sm;
    const int b0 = mp0 / NPIX, rp0 = mp0 % NPIX;
    const int py0 = rp0 / WW, px0 = rp0 % WW;
    const int mp1 = m0 + 64 + sm;
    const int b1_ = mp1 / NPIX, rp1 = mp1 % NPIX;
    const int py1 = rp1 / WW, px1 = rp1 % WW;
    for (int step = 0; step < 18; ++step) {
        const int p = step >> 1, ch = (step & 1) * 32;
        const int dy = p / 3 - 1, dx = p % 3 - 1;
        s8v av;
        if (t < 64) av = *(const s8v*)(wb + (t >> 2) * 576 + p * 64 + ch + (t & 3) * 8);
        s8v bv0, bv1;
        #pragma unroll
        for (int j = 0; j < 8; j++) { bv0[j] = 0; bv1[j] = 0; }
        int yy = py0 + dy, xx = px0 + dx;
        if (yy >= 0 && yy < HH && xx >= 0 && xx < WW)
            bv0 = *(const s8v*)((const short*)h2 + ((size_t)which * 51200 + (size_t)b0 * NPIX + yy * WW + xx) * 64 + ch + sq);
        yy = py1 + dy; xx = px1 + dx;
        if (yy >= 0 && yy < HH && xx >= 0 && xx < WW)
            bv1 = *(const s8v*)((const short*)h2 + ((size_t)which * 51200 + (size_t)b1_ * NPIX + yy * WW + xx) * 64 + ch + sq);
        __syncthreads();
        if (t < 64) *(s8v*)((short*)Al + (t >> 2) * LP + (t & 3) * 8) = av;
        *(s8v*)((short*)Bl + sm * LP + sq) = bv0;
        *(s8v*)((short*)Bl + (64 + sm) * LP + sq) = bv1;
        __syncthreads();
        s8v af = *(const s8v*)((const short*)Al + (lane & 15) * LP + (lane >> 4) * 8);
        #pragma unroll
        for (int mf = 0; mf < 2; ++mf) {
            s8v bf = *(const s8v*)((const short*)Bl + (wv * 32 + mf * 16 + (lane & 15)) * LP + (lane >> 4) * 8);
            acc[mf] = __builtin_amdgcn_mfma_f32_16x16x32_bf16(af, bf, acc[mf], 0, 0, 0);
        }
    }
    #pragma unroll
    for (int mf = 0; mf < 2; ++mf) {
        int mm = m0 + wv * 32 + mf * 16 + (lane & 15);
        if (which == 0) {
            f4v hilo;
            #pragma unroll
            for (int c = 0; c < 4; ++c)
                hilo[c] = acc[mf][c] + __shfl_xor(acc[mf][c], 32);   // n (hi) + n+8 (lo)
            if (lane < 32) {
                int nb = (lane >> 4) * 4;
                u4v hs, ls;
                float ss = 0.f;
                #pragma unroll
                for (int c = 0; c < 4; ++c) {
                    float v = hilo[c] + eb3[nb + c];
                    unsigned short h = f2bf(v);
                    hs[c] = h;
                    ls[c] = f2bf(v - bf2f(h));
                    ss += v * v;
                }
                *(u4v*)(xeH + (size_t)mm * 8 + nb) = hs;
                *(u4v*)(xeL + (size_t)mm * 8 + nb) = ls;
                ss += __shfl_xor(ss, 16);      // combine ch 0-3 with 4-7
                if (lane < 16) splane[mm] = ss;
            }
        } else {
            if ((lane >> 4) == 0)
                ltm[mm] = acc[mf][0] + acc[mf][1] + tb3[0];          // n0 hi + n1 lo
        }
    }
}

// ---------- gram (blocks <620) + ynt (blocks >=620), one launch ----------
__global__ __launch_bounds__(256) void gram_ynt_k(const unsigned short* __restrict__ xeH,
                                                  const unsigned short* __restrict__ xeL,
                                                  const float* __restrict__ splane,
                                                  const float* __restrict__ ltm,
                                                  float* __restrict__ dotsC,
                                                  float* __restrict__ yn,
                                                  float* __restrict__ tempv) {
    if (blockIdx.x >= GRAMBLKS) {    // ynt path: wave per site
        int wv = threadIdx.x >> 6, lane = threadIdx.x & 63;
        int wid = (blockIdx.x - GRAMBLKS) * 4 + wv;
        if (wid >= SITES) return;
        int b = wid / NSITE; int ij = wid % NSITE;
        int i1 = ij / N2, i2 = ij % N2;
        float s1 = 0.f, s2 = 0.f;
        for (int p = lane; p < 100; p += 64) {
            int rr = p / 10, q = p % 10;
            int idx = b * NPIX + (i1 * STR + rr) * WW + i2 * STR + q;
            s1 += splane[idx];
            s2 += ltm[idx];
        }
        #pragma unroll
        for (int o = 32; o; o >>= 1) { s1 += __shfl_xor(s1, o); s2 += __shfl_xor(s2, o); }
        if (lane == 0) {
            yn[wid] = s1;
            tempv[wid] = expf(s2 * (1.f / 100.f));
        }
        return;
    }
    __shared__ unsigned short AsH[32 * GP], AsL[32 * GP];
    __shared__ unsigned short BsH[256 * GP], BsL[256 * GP];
    int blk = blockIdx.x;                  // ((b*31+i1)*2+nh)*KSPLIT + kc
    int kc = blk % KSPLIT; int r = blk / KSPLIT;
    int nh = r & 1; r >>= 1;
    int b = r / N1, i1 = r % N1;
    int b1 = min(max(i1 - 7, 0), 16);
    int t = threadIdx.x;
    int wv = t >> 6, lane = t & 63;
    f4v acc[2][4];
    #pragma unroll
    for (int mt = 0; mt < 2; ++mt)
        #pragma unroll
        for (int nt = 0; nt < 4; ++nt) { f4v z = {0.f,0.f,0.f,0.f}; acc[mt][nt] = z; }
    const size_t pbase = (size_t)b * NPIX;
    for (int ks = kc * 5; ks < kc * 5 + 5; ++ks) {
        __syncthreads();
        {   // stage A: rows = i2 (0..31), pixel p = ks*4+seg
            int idx = t & 127;
            int row = idx >> 2, seg = idx & 3;
            int p = ks * 4 + seg;
            int rr = p / 10, q = p - rr * 10;
            u8v v;
            #pragma unroll
            for (int u = 0; u < 8; ++u) v[u] = 0;
            if (row < 31) {
                size_t a = (pbase + (size_t)(i1 * STR + rr) * WW + row * STR + q) * 8;
                v = *(const u8v*)((t < 128 ? xeH : xeL) + a);
            }
            *(u8v*)((t < 128 ? AsH : AsL) + row * GP + seg * 8) = v;
        }
        #pragma unroll
        for (int rep = 0; rep < 8; ++rep) {   // stage B: rows = dj,j2
            int idx = t + rep * 256;
            int isH = idx < 1024;
            int id2 = idx & 1023;
            int row = id2 >> 2, seg = id2 & 3;
            int dj = nh * 8 + (row >> 5), j2 = row & 31;
            int p = ks * 4 + seg;
            int rr = p / 10, q = p - rr * 10;
            u8v v;
            #pragma unroll
            for (int u = 0; u < 8; ++u) v[u] = 0;
            if (dj < 15 && j2 < 31) {
                size_t a = (pbase + (size_t)((b1 + dj) * STR + rr) * WW + j2 * STR + q) * 8;
                v = *(const u8v*)((isH ? xeH : xeL) + a);
            }
            *(u8v*)((isH ? BsH : BsL) + row * GP + seg * 8) = v;
        }
        __syncthreads();
        s8v afH[2], afL[2], bfH[4], bfL[4];
        #pragma unroll
        for (int mt = 0; mt < 2; ++mt) {
            int ar = mt * 16 + (lane & 15);
            afH[mt] = *(const s8v*)((const short*)AsH + ar * GP + (lane >> 4) * 8);
            afL[mt] = *(const s8v*)((const short*)AsL + ar * GP + (lane >> 4) * 8);
        }
        #pragma unroll
        for (int nt = 0; nt < 4; ++nt) {
            int br = wv * 64 + nt * 16 + (lane & 15);
            bfH[nt] = *(const s8v*)((const short*)BsH + br * GP + (lane >> 4) * 8);
            bfL[nt] = *(const s8v*)((const short*)BsL + br * GP + (lane >> 4) * 8);
        }
        #pragma unroll
        for (int mt = 0; mt < 2; ++mt)
            #pragma unroll
            for (int nt = 0; nt < 4; ++nt) {
                acc[mt][nt] = __builtin_amdgcn_mfma_f32_16x16x32_bf16(afH[mt], bfH[nt], acc[mt][nt], 0, 0, 0);
                acc[mt][nt] = __builtin_amdgcn_mfma_f32_16x16x32_bf16(afH[mt], bfL[nt], acc[mt][nt], 0, 0, 0);
                acc[mt][nt] = __builtin_amdgcn_mfma_f32_16x16x32_bf16(afL[mt], bfH[nt], acc[mt][nt], 0, 0, 0);
            }
    }
    float* dk = dotsC + (size_t)kc * SITES * NOFF;
    #pragma unroll
    for (int mt = 0; mt < 2; ++mt) {
        int i2b = mt * 16 + (lane >> 4) * 4;
        #pragma unroll
        for (int nt = 0; nt < 4; ++nt) {
            int n = wv * 64 + nt * 16 + (lane & 15);
            int dj = nh * 8 + (n >> 5), j2 = n & 31;
            if (dj >= 15 || j2 >= 31) continue;
            #pragma unroll
            for (int c = 0; c < 4; ++c) {
                int i2 = i2b + c;
                if (i2 >= 31) continue;
                int b2 = min(max(i2 - 7, 0), 16);
                int dc = j2 - b2;
                if (dc < 0 || dc >= SWIN) continue;
                size_t site = (size_t)((b * N1 + i1) * N2 + i2);
                dk[site * NOFF + dj * SWIN + dc] = acc[mt][nt][c];
            }
        }
    }
}

// ---------- fused softmax + A-build: wave per site writes Aglob rows directly ----------
__global__ __launch_bounds__(256) void softmax_awrite_k(const float* __restrict__ dotsC,
                                                        const float* __restrict__ yn,
                                                        const float* __restrict__ tempv,
                                                        unsigned short* __restrict__ Aglob) {
    __shared__ float sw[4][228];
    int wv = threadIdx.x >> 6, lane = threadIdx.x & 63;
    int wid = blockIdx.x * 4 + wv;
    bool active = (wid < SITES);
    int wids = active ? wid : (SITES - 1);
    int b = wids / NSITE; int ij = wids % NSITE;
    int i1 = ij / N2, i2 = ij % N2;
    int b1 = min(max(i1 - 7, 0), 16);
    int b2 = min(max(i2 - 7, 0), 16);
    int pglob = i2 >> 1, s = i2 & 1;
    unsigned short* Abase = Aglob + (size_t)((b * N1 + i1) * 256) * KP;
    float yns = yn[wids];
    float tvi = 1.f / tempv[wids];
    float lg[4];
    #pragma unroll
    for (int r = 0; r < 4; ++r) {
        int t = lane + 64 * r;
        lg[r] = -1e9f;
        if (t < NOFF) {
            float dot = 0.f;
            #pragma unroll
            for (int kc = 0; kc < KSPLIT; ++kc)
                dot += dotsC[((size_t)kc * SITES + wids) * NOFF + t];
            int dj = t / SWIN, dc = t % SWIN;
            int j1 = b1 + dj, j2 = b2 + dc;
            float xn = yn[(b * N1 + j1) * N2 + j2];
            float d = yns + xn - 2.f * dot;
            lg[r] = -d * tvi;
            if (j1 == i1 && j2 == i2) lg[r] = -1e9f;
        }
    }
    for (int k = 0; k < KK; ++k) {
        float m = fmaxf(fmaxf(lg[0], lg[1]), fmaxf(lg[2], lg[3]));
        #pragma unroll
        for (int o = 32; o; o >>= 1) m = fmaxf(m, __shfl_xor(m, o));
        float ex[4]; float ssum = 0.f;
        #pragma unroll
        for (int r = 0; r < 4; ++r) { ex[r] = __expf(lg[r] - m); ssum += ex[r]; }
        #pragma unroll
        for (int o = 32; o; o >>= 1) ssum += __shfl_xor(ssum, o);
        float inv = 1.f / ssum;
        #pragma unroll
        for (int r = 0; r < 4; ++r) {
            float wgt = ex[r] * inv;
            int t = lane + 64 * r;
            if (t < NOFF) sw[wv][t] = wgt;
            lg[r] += log1pf(-fminf(wgt, 1.f - 1e-6f));
        }
        __syncthreads();
        if (active && lane < 60) {
            u8v o;
            #pragma unroll
            for (int u = 0; u < 8; ++u) {
                int n = lane * 8 + u;
                int dj = n >> 5, j2 = n & 31;
                int dc = j2 - b2;
                o[u] = (j2 < 31 && dc >= 0 && dc < SWIN) ? f2bf(sw[wv][dj * SWIN + dc]) : (unsigned short)0;
            }
            int m_ = 16 * pglob + k + 7 * s;
            *(u8v*)(Abase + (size_t)m_ * KP + lane * 8) = o;
        }
        __syncthreads();
    }
    if (active && s == 0 && lane < 60) {
        u8v z;
        #pragma unroll
        for (int u = 0; u < 8; ++u) z[u] = 0;
        *(u8v*)(Abase + (size_t)(16 * pglob + 14) * KP + lane * 8) = z;
        *(u8v*)(Abase + (size_t)(16 * pglob + 15) * KP + lane * 8) = z;
        if (i2 == 30) {
            #pragma unroll
            for (int sl = 7; sl < 14; ++sl)
                *(u8v*)(Abase + (size_t)(16 * 15 + sl) * KP + lane * 8) = z;
        }
    }
}

// ---------- agg GEMM: per (b,i1): C[256 m][800 e] = A[256x480] * ypT-slice^T ----------
__global__ __launch_bounds__(256) void agg_gemm_k(const unsigned short* __restrict__ Aglob,
                                                  const unsigned short* __restrict__ ypT,
                                                  unsigned short* __restrict__ zbuf) {
    __shared__ unsigned short As[128 * 40];
    __shared__ unsigned short Bs[160 * 40];
    int blk = blockIdx.x;                     // b*310 + i1*10 + mh*5 + nc
    int b = blk / 310; int r = blk % 310;
    int i1 = r / 10; int r2 = r % 10;
    int mh = r2 / 5, nc = r2 % 5;
    int b1 = min(max(i1 - 7, 0), 16);
    int t = threadIdx.x;
    int wv = t >> 6, lane = t & 63;
    int wm = (wv & 1) * 64, we = (wv >> 1) * 80;
    const unsigned short* Ab = Aglob + ((size_t)(b * N1 + i1) * 256 + mh * 128) * KP;
    const unsigned short* Bb = ypT + ((size_t)b * 800 + nc * 160) * COLP + b1 * 32;
    f4v accr[4][5];
    #pragma unroll
    for (int mt = 0; mt < 4; ++mt)
        #pragma unroll
        for (int et = 0; et < 5; ++et) { f4v z = {0.f,0.f,0.f,0.f}; accr[mt][et] = z; }
    for (int ks = 0; ks < 15; ++ks) {
        __syncthreads();
        #pragma unroll
        for (int it = 0; it < 2; ++it) {
            int idx = t + it * 256;
            int row = idx >> 2, seg = idx & 3;
            *(u8v*)(As + row * 40 + seg * 8) = *(const u8v*)(Ab + (size_t)row * KP + ks * 32 + seg * 8);
        }
        #pragma unroll
        for (int it = 0; it < 3; ++it) {
            int idx = t + it * 256;
            if (idx < 640) {
                int row = idx >> 2, seg = idx & 3;
                *(u8v*)(Bs + row * 40 + seg * 8) = *(const u8v*)(Bb + (size_t)row * COLP + ks * 32 + seg * 8);
            }
        }
        __syncthreads();
        s8v af[4], bf[5];
        #pragma unroll
        for (int mt = 0; mt < 4; ++mt)
            af[mt] = *(const s8v*)((const short*)As + (wm + mt * 16 + (lane & 15)) * 40 + (lane >> 4) * 8);
        #pragma unroll
        for (int et = 0; et < 5; ++et)
            bf[et] = *(const s8v*)((const short*)Bs + (we + et * 16 + (lane & 15)) * 40 + (lane >> 4) * 8);
        #pragma unroll
        for (int mt = 0; mt < 4; ++mt)
            #pragma unroll
            for (int et = 0; et < 5; ++et)
                accr[mt][et] = __builtin_amdgcn_mfma_f32_16x16x32_bf16(af[mt], bf[et], accr[mt][et], 0, 0, 0);
    }
    unsigned short* zb = zbuf + ((size_t)(b * N1 + i1) * 256 + mh * 128) * 800 + nc * 160;
    #pragma unroll
    for (int mt = 0; mt < 4; ++mt) {
        int mrow = wm + mt * 16 + (lane >> 4) * 4;
        #pragma unroll
        for (int et = 0; et < 5; ++et) {
            int ecol = we + et * 16 + (lane & 15);
            #pragma unroll
            for (int c = 0; c < 4; ++c)
                zb[(size_t)(mrow + c) * 800 + ecol] = f2bf(accr[mt][et][c]);
        }
    }
}

// ---------- finalize: thread per (b,pixel), all 64 channels ----------
__global__ __launch_bounds__(256) void finalize_k(const unsigned short* __restrict__ zbuf,
                                                  const float* __restrict__ xd,
                                                  float* __restrict__ out) {
    int pid = blockIdx.x * 256 + threadIdx.x;      // b*NPIX + pix
    if (pid >= BN * NPIX) return;
    int b = pid / NPIX, pix = pid % NPIX;
    int h = pix / WW, w_ = pix % WW;
    int lo1 = max(0, (h - 5) / 5),  hi1 = min(30, h / 5);
    int lo2 = max(0, (w_ - 5) / 5), hi2 = min(30, w_ / 5);
    float cntinv = 1.f / (float)((hi1 - lo1 + 1) * (hi2 - lo2 + 1));
    float xv[8];
    #pragma unroll
    for (int cd = 0; cd < 8; ++cd) {
        xv[cd] = xd[((size_t)(b * 8 + cd)) * NPIX + pix];
        out[((size_t)(b * 64 + cd)) * NPIX + pix] = xv[cd];
    }
    for (int k = 0; k < KK; ++k) {
        float s[8];
        #pragma unroll
        for (int cd = 0; cd < 8; ++cd) s[cd] = 0.f;
        for (int i1 = lo1; i1 <= hi1; ++i1) {
            int pi = h - 5 * i1;
            for (int i2 = lo2; i2 <= hi2; ++i2) {
                int pj = w_ - 5 * i2;
                int m = 16 * (i2 >> 1) + k + 7 * (i2 & 1);
                const unsigned short* zp = zbuf + ((size_t)(b * N1 + i1) * 256 + m) * 800 + (pi * 10 + pj) * 8;
                u8v zv = *(const u8v*)zp;
                #pragma unroll
                for (int cd = 0; cd < 8; ++cd) s[cd] += bf2f(zv[cd]);
            }
        }
        #pragma unroll
        for (int cd = 0; cd < 8; ++cd)
            out[((size_t)(b * 64 + (k + 1) * 8 + cd)) * NPIX + pix] = s[cd] * cntinv - xv[cd];
    }
}

extern "C" void kernel_launch(void* const* d_in, const int* in_sizes, int n_in,
                              void* d_out, int out_size, void* d_ws, size_t ws_size,
                              hipStream_t stream) {
    (void)in_sizes; (void)n_in; (void)out_size; (void)ws_size;
    const float* x_data = (const float*)d_in[0];
    const float* x_faet = (const float*)d_in[1];
    const float* ew1 = (const float*)d_in[2];  const float* eb1 = (const float*)d_in[3];
    const float* ew2 = (const float*)d_in[4];  const float* eb2 = (const float*)d_in[5];
    const float* ew3 = (const float*)d_in[6];  const float* eb3 = (const float*)d_in[7];
    const float* tw1 = (const float*)d_in[8];  const float* tb1 = (const float*)d_in[9];
    const float* tw2 = (const float*)d_in[10]; const float* tb2 = (const float*)d_in[11];
    const float* tw3 = (const float*)d_in[12]; const float* tb3 = (const float*)d_in[13];
    float* out = (float*)d_out;

    // workspace layout (bytes), total 44.8 MB (same as R11):
    char* base = (char*)d_ws;
    unsigned short* h1 = (unsigned short*)(base);
    unsigned short* h2 = (unsigned short*)(base + 13107200);
    unsigned short* wp1 = (unsigned short*)(base + 13107200);   // dead before conv2 writes h2
    unsigned short* wp = (unsigned short*)(base + 26214400);
    float* yn    = (float*)(base + 26361856);
    float* tempv = (float*)(base + 26370048);
    unsigned short* ypT = (unsigned short*)(base + 26378240);
    unsigned short* xeH = (unsigned short*)(base + 29552640);
    unsigned short* xeL = (unsigned short*)(base + 30371840);
    float* ltm    = (float*)(base + 31191040);
    float* splane = (float*)(base + 31395840);
    unsigned short* wp3 = (unsigned short*)(base + 37546240);
    unsigned short* Aglob = (unsigned short*)(base + 29552640);
    float* dotsC = (float*)h2;
    unsigned short* zbuf = (unsigned short*)base;

    prep_k<<<408, 256, 0, stream>>>(ew2, tw2, ew1, tw1, ew3, tw3, wp, wp1, wp3);
    conv1_ypt_k<<<800 + 1600, 256, 0, stream>>>(x_faet, x_data, wp1, eb1, tb1, h1, ypT);
    conv2_mfma_k<<<dim3(400, 2), 256, 0, stream>>>(h1, wp, eb2, tb2, h2);
    conv3_mfma_k<<<dim3(400, 2), 256, 0, stream>>>(h2, wp3, eb3, tb3, xeH, xeL, splane, ltm);

    gram_ynt_k<<<GRAMBLKS + YNTBLKS, 256, 0, stream>>>(xeH, xeL, splane, ltm, dotsC, yn, tempv);
    softmax_awrite_k<<<YNTBLKS, 256, 0, stream>>>(dotsC, yn, tempv, Aglob);

    agg_gemm_k<<<BN * 310, 256, 0, stream>>>(Aglob, ypT, zbuf);
    finalize_k<<<(BN * NPIX + 255) / 256, 256, 0, stream>>>(zbuf, x_data, out);
}

// Round 15
// 158.673 us; speedup vs baseline: 1.0030x; 1.0021x over previous
//
#include <hip/hip_runtime.h>
#include <math.h>

#define BN 2
#define HH 160
#define WW 160
#define CDATA 8
#define PS 10
#define STR 5
#define N1 31
#define N2 31
#define NSITE (N1*N2)
#define SITES (BN*NSITE)
#define SWIN 15
#define NOFF 225
#define KK 7
#define EDIM 800
#define NPIX 25600          // HH*WW
#define LP 40               // conv1/conv3 LDS pitch (ushorts)
#define LP2 72              // conv2 LDS pitch (64 k + 8 pad)
#define KP 480              // agg A k-pitch (= 15 dj * 32 j2-slots)
#define COLP 992            // ypT col pitch (31 j1 * 32 j2-slots)
#define GP 34               // gram LDS pitch (ushorts): 32 k + 2 pad
#define KSPLIT 5            // gram K-split (5 x 160)
#define GRAMBLKS (BN*N1*2*KSPLIT)   // 620
#define YNTBLKS ((SITES+3)/4)       // 481

typedef __attribute__((ext_vector_type(8))) short s8v;
typedef __attribute__((ext_vector_type(8))) unsigned short u8v;
typedef __attribute__((ext_vector_type(4))) unsigned short u4v;
typedef __attribute__((ext_vector_type(4))) float f4v;

__device__ __forceinline__ unsigned short f2bf(float f) {
    unsigned u = __float_as_uint(f);
    return (unsigned short)((u + 0x7FFFu + ((u >> 16) & 1u)) >> 16);
}
__device__ __forceinline__ float bf2f(unsigned short h) {
    return __uint_as_float(((unsigned)h) << 16);
}

// ---------- prep: w2 pack + w1 pack + w3 hi/lo pack (ypT moved into conv1 launch) ----------
__global__ __launch_bounds__(256) void prep_k(const float* __restrict__ ew2,
                                              const float* __restrict__ tw2,
                                              const float* __restrict__ ew1,
                                              const float* __restrict__ tw1,
                                              const float* __restrict__ ew3,
                                              const float* __restrict__ tw3,
                                              unsigned short* __restrict__ wp,
                                              unsigned short* __restrict__ wp1,
                                              unsigned short* __restrict__ wp3) {
    int blk = blockIdx.x;
    int t = threadIdx.x;
    if (blk < 288) {             // w2 pack [2][n=64][k=576], k=tap*64+c
        int idx = blk * 256 + t;
        int which = idx / (64 * 576); int r = idx % (64 * 576);
        int n = r / 576, k = r % 576;
        int p = k / 64, c = k % 64;
        const float* w = which ? tw2 : ew2;
        wp[idx] = f2bf(w[(n * 64 + c) * 9 + p]);
    } else if (blk < 336) {      // w1 pack [n=128][k=96], k=tap*8+c, taps>=9 zero
        int idx = (blk - 288) * 256 + t;
        if (idx < 128 * 96) {
            int n = idx / 96, k = idx % 96;
            int tap = k >> 3, c = k & 7;
            unsigned short v = 0;
            if (tap < 9) {
                const float* w = (n < 64) ? ew1 : tw1;
                v = f2bf(w[((n & 63) * 8 + c) * 9 + tap]);
            }
            wp1[idx] = v;
        }
    } else {                     // w3 pack [2][16][576]: hi/lo weight split in n
        int idx = (blk - 336) * 256 + t;
        if (idx < 2 * 16 * 576) {
            int which = idx / (16 * 576); int r = idx % (16 * 576);
            int n = r / 576, k = r % 576;
            int tap = k / 64, c = k % 64;
            float w = 0.f; bool lo = false;
            if (which == 0) { w = ew3[((n & 7) * 64 + c) * 9 + tap]; lo = (n >= 8); }
            else if (n < 2) { w = tw3[c * 9 + tap]; lo = (n == 1); }
            unsigned short hi = f2bf(w);
            wp3[idx] = lo ? f2bf(w - bf2f(hi)) : hi;
            if (which == 1 && n >= 2) wp3[idx] = 0;
        }
    }
}

// ---------- conv1 (blocks <800) + ypT build (blocks >=800), one launch ----------
__global__ __launch_bounds__(256) void conv1_ypt_k(const float* __restrict__ xf,
                                                   const float* __restrict__ xd,
                                                   const unsigned short* __restrict__ wp1,
                                                   const float* __restrict__ eb1,
                                                   const float* __restrict__ tb1,
                                                   unsigned short* __restrict__ h1,
                                                   unsigned short* __restrict__ ypT) {
    const int t = threadIdx.x;
    if (blockIdx.x >= 800) {     // ypT[b][e][j1*32+j2] bf16, zero at j2==31
        int row = blockIdx.x - 800;        // b*800 + e
        int b = row / 800, e = row % 800;
        int cd = e & 7, pp = e >> 3;
        int pi = pp / 10, pj = pp % 10;
        const float* src = xd + ((size_t)(b * 8 + cd) * HH + pi) * WW + pj;
        unsigned short* dst = ypT + (size_t)row * COLP;
        for (int it = 0; it < 4; ++it) {
            int col = it * 256 + t;
            if (col < COLP) {
                int j1 = col >> 5, j2 = col & 31;
                unsigned short v = 0;
                if (j2 < 31) v = f2bf(src[(j1 * 5) * WW + j2 * 5]);
                dst[col] = v;
            }
        }
        return;
    }
    __shared__ unsigned short Al[128 * LP];   // n x k32
    __shared__ unsigned short Bl[64 * LP];    // m x k32
    const int m0 = blockIdx.x * 64;
    const int wv = t >> 6, lane = t & 63;
    f4v acc[2][4];
    #pragma unroll
    for (int fj = 0; fj < 2; ++fj)
        #pragma unroll
        for (int fi = 0; fi < 4; ++fi) { f4v z = {0.f,0.f,0.f,0.f}; acc[fj][fi] = z; }
    const int mp = m0 + (t >> 2);
    const int b = mp / NPIX, rp = mp % NPIX;
    const int py = rp / WW, px = rp % WW;
    for (int ks = 0; ks < 3; ++ks) {
        int tap = ks * 4 + (t & 3);
        int dy = tap / 3 - 1, dx = tap % 3 - 1;
        int yy = py + dy, xx = px + dx;
        bool ok = (tap < 9) && yy >= 0 && yy < HH && xx >= 0 && xx < WW;
        u8v bv;
        #pragma unroll
        for (int c = 0; c < 8; ++c)
            bv[c] = ok ? f2bf(xf[((size_t)(b * 8 + c)) * NPIX + yy * WW + xx]) : 0;
        __syncthreads();
        *(u8v*)(Bl + (t >> 2) * LP + (t & 3) * 8) = bv;
        #pragma unroll
        for (int it = 0; it < 2; ++it) {
            int idx = t + it * 256;
            int row = idx >> 2, seg = idx & 3;
            *(u8v*)(Al + row * LP + seg * 8) = *(const u8v*)(wp1 + row * 96 + ks * 32 + seg * 8);
        }
        __syncthreads();
        s8v af[2], bf[4];
        #pragma unroll
        for (int fj = 0; fj < 2; ++fj)
            af[fj] = *(const s8v*)((const short*)Al + (wv * 32 + fj * 16 + (lane & 15)) * LP + (lane >> 4) * 8);
        #pragma unroll
        for (int fi = 0; fi < 4; ++fi)
            bf[fi] = *(const s8v*)((const short*)Bl + (fi * 16 + (lane & 15)) * LP + (lane >> 4) * 8);
        #pragma unroll
        for (int fj = 0; fj < 2; ++fj)
            #pragma unroll
            for (int fi = 0; fi < 4; ++fi)
                acc[fj][fi] = __builtin_amdgcn_mfma_f32_16x16x32_bf16(af[fj], bf[fi], acc[fj][fi], 0, 0, 0);
    }
    #pragma unroll
    for (int fj = 0; fj < 2; ++fj) {
        int nb = wv * 32 + fj * 16 + (lane >> 4) * 4;
        float bias4[4];
        #pragma unroll
        for (int c = 0; c < 4; ++c) {
            int n = nb + c;
            bias4[c] = (n < 64) ? eb1[n] : tb1[n - 64];
        }
        #pragma unroll
        for (int fi = 0; fi < 4; ++fi) {
            int mm = m0 + fi * 16 + (lane & 15);
            ushort4 o;
            o.x = f2bf(fmaxf(acc[fj][fi][0] + bias4[0], 0.f));
            o.y = f2bf(fmaxf(acc[fj][fi][1] + bias4[1], 0.f));
            o.z = f2bf(fmaxf(acc[fj][fi][2] + bias4[2], 0.f));
            o.w = f2bf(fmaxf(acc[fj][fi][3] + bias4[3], 0.f));
            *(ushort4*)(h1 + (size_t)mm * 128 + nb) = o;
        }
    }
}

// ---------- conv2: bf16 MFMA implicit GEMM, M=128 tile, K-step 64 (9 barrier-pairs) ----------
__global__ __launch_bounds__(256) void conv2_mfma_k(const unsigned short* __restrict__ h1,
                                                    const unsigned short* __restrict__ wp,
                                                    const float* __restrict__ eb2,
                                                    const float* __restrict__ tb2,
                                                    unsigned short* __restrict__ h2) {
    __shared__ unsigned short Al[64 * LP2];    // n=64 x k64
    __shared__ unsigned short Bl[128 * LP2];   // m=128 x k64
    const int t = threadIdx.x;
    const int which = blockIdx.y;
    const int m0 = blockIdx.x * 128;
    const int wv = t >> 6, lane = t & 63;
    f4v acc[4][2];   // [nf][mf]
    #pragma unroll
    for (int nf = 0; nf < 4; ++nf)
        #pragma unroll
        for (int mf = 0; mf < 2; ++mf) { f4v z = {0.f,0.f,0.f,0.f}; acc[nf][mf] = z; }
    const unsigned short* wb = wp + (size_t)which * 64 * 576;
    const int sm = t >> 2, sq = (t & 3) * 8;
    const int mp0 = m0 + sm;
    const int b0 = mp0 / NPIX, rp0 = mp0 % NPIX;
    const int py0 = rp0 / WW, px0 = rp0 % WW;
    const int mp1 = m0 + 64 + sm;
    const int b1_ = mp1 / NPIX, rp1 = mp1 % NPIX;
    const int py1 = rp1 / WW, px1 = rp1 % WW;
    for (int p = 0; p < 9; ++p) {
        const int dy = p / 3 - 1, dx = p % 3 - 1;
        s8v av[2], bv0[2], bv1[2];
        #pragma unroll
        for (int hh = 0; hh < 2; ++hh) {
            av[hh] = *(const s8v*)(wb + sm * 576 + p * 64 + hh * 32 + sq);
            #pragma unroll
            for (int j = 0; j < 8; j++) { bv0[hh][j] = 0; bv1[hh][j] = 0; }
        }
        int yy = py0 + dy, xx = px0 + dx;
        if (yy >= 0 && yy < HH && xx >= 0 && xx < WW) {
            const short* src = (const short*)h1 + ((size_t)b0 * NPIX + yy * WW + xx) * 128 + which * 64 + sq;
            bv0[0] = *(const s8v*)src; bv0[1] = *(const s8v*)(src + 32);
        }
        yy = py1 + dy; xx = px1 + dx;
        if (yy >= 0 && yy < HH && xx >= 0 && xx < WW) {
            const short* src = (const short*)h1 + ((size_t)b1_ * NPIX + yy * WW + xx) * 128 + which * 64 + sq;
            bv1[0] = *(const s8v*)src; bv1[1] = *(const s8v*)(src + 32);
        }
        __syncthreads();
        #pragma unroll
        for (int hh = 0; hh < 2; ++hh) {
            *(s8v*)((short*)Al + sm * LP2 + hh * 32 + sq) = av[hh];
            *(s8v*)((short*)Bl + sm * LP2 + hh * 32 + sq) = bv0[hh];
            *(s8v*)((short*)Bl + (64 + sm) * LP2 + hh * 32 + sq) = bv1[hh];
        }
        __syncthreads();
        #pragma unroll
        for (int kk = 0; kk < 2; ++kk) {
            s8v af[4], bf[2];
            #pragma unroll
            for (int nf = 0; nf < 4; ++nf)
                af[nf] = *(const s8v*)((const short*)Al + (nf * 16 + (lane & 15)) * LP2 + kk * 32 + (lane >> 4) * 8);
            #pragma unroll
            for (int mf = 0; mf < 2; ++mf)
                bf[mf] = *(const s8v*)((const short*)Bl + (wv * 32 + mf * 16 + (lane & 15)) * LP2 + kk * 32 + (lane >> 4) * 8);
            #pragma unroll
            for (int nf = 0; nf < 4; ++nf)
                #pragma unroll
                for (int mf = 0; mf < 2; ++mf)
                    acc[nf][mf] = __builtin_amdgcn_mfma_f32_16x16x32_bf16(af[nf], bf[mf], acc[nf][mf], 0, 0, 0);
        }
    }
    const float* bias = which ? tb2 : eb2;
    #pragma unroll
    for (int nf = 0; nf < 4; ++nf) {
        int nb = nf * 16 + (lane >> 4) * 4;
        f4v bv4 = *(const f4v*)(bias + nb);
        #pragma unroll
        for (int mf = 0; mf < 2; ++mf) {
            int mm = m0 + wv * 32 + mf * 16 + (lane & 15);
            ushort4 o;
            o.x = f2bf(fmaxf(acc[nf][mf][0] + bv4[0], 0.f));
            o.y = f2bf(fmaxf(acc[nf][mf][1] + bv4[1], 0.f));
            o.z = f2bf(fmaxf(acc[nf][mf][2] + bv4[2], 0.f));
            o.w = f2bf(fmaxf(acc[nf][mf][3] + bv4[3], 0.f));
            *(ushort4*)(h2 + ((size_t)which * 51200 + mm) * 64 + nb) = o;
        }
    }
}

// ---------- conv3: bf16 MFMA, N=16 weight hi/lo; emits xeH/xeL bf16 NHWC + splane + ltm ----------
__global__ __launch_bounds__(256) void conv3_mfma_k(const unsigned short* __restrict__ h2,
                                                    const unsigned short* __restrict__ wp3,
                                                    const float* __restrict__ eb3,
                                                    const float* __restrict__ tb3,
                                                    unsigned short* __restrict__ xeH,
                                                    unsigned short* __restrict__ xeL,
                                                    float* __restrict__ splane,
                                                    float* __restrict__ ltm) {
    __shared__ unsigned short Al[16 * LP];
    __shared__ unsigned short Bl[128 * LP];
    const int t = threadIdx.x;
    const int which = blockIdx.y;
    const int m0 = blockIdx.x * 128;
    const int wv = t >> 6, lane = t & 63;
    f4v acc[2];
    { f4v z = {0.f,0.f,0.f,0.f}; acc[0] = z; acc[1] = z; }
    const unsigned short* wb = wp3 + (size_t)which * 16 * 576;
    const int sm = t >> 2, sq = (t & 3) * 8;
    const int mp0 = m0 + sm;
    const int b0 = mp0 / NPIX, rp0 = mp0 % NPIX;
    const int py0 = rp0 / WW, px0 = rp0 % WW;
    const int mp1 = m0 + 64 + sm;
    const int b1_ = mp1 / NPIX, rp1 = mp1 % NPIX;
    const int py1 = rp1 / WW, px1 = rp1 % WW;
    for (int step = 0; step < 18; ++step) {
        const int p = step >> 1, ch = (step & 1) * 32;
        const int dy = p / 3 - 1, dx = p % 3 - 1;
        s8v av;
        if (t < 64) av = *(const s8v*)(wb + (t >> 2) * 576 + p * 64 + ch + (t & 3) * 8);
        s8v bv0, bv1;
        #pragma unroll
        for (int j = 0; j < 8; j++) { bv0[j] = 0; bv1[j] = 0; }
        int yy = py0 + dy, xx = px0 + dx;
        if (yy >= 0 && yy < HH && xx >= 0 && xx < WW)
            bv0 = *(const s8v*)((const short*)h2 + ((size_t)which * 51200 + (size_t)b0 * NPIX + yy * WW + xx) * 64 + ch + sq);
        yy = py1 + dy; xx = px1 + dx;
        if (yy >= 0 && yy < HH && xx >= 0 && xx < WW)
            bv1 = *(const s8v*)((const short*)h2 + ((size_t)which * 51200 + (size_t)b1_ * NPIX + yy * WW + xx) * 64 + ch + sq);
        __syncthreads();
        if (t < 64) *(s8v*)((short*)Al + (t >> 2) * LP + (t & 3) * 8) = av;
        *(s8v*)((short*)Bl + sm * LP + sq) = bv0;
        *(s8v*)((short*)Bl + (64 + sm) * LP + sq) = bv1;
        __syncthreads();
        s8v af = *(const s8v*)((const short*)Al + (lane & 15) * LP + (lane >> 4) * 8);
        #pragma unroll
        for (int mf = 0; mf < 2; ++mf) {
            s8v bf = *(const s8v*)((const short*)Bl + (wv * 32 + mf * 16 + (lane & 15)) * LP + (lane >> 4) * 8);
            acc[mf] = __builtin_amdgcn_mfma_f32_16x16x32_bf16(af, bf, acc[mf], 0, 0, 0);
        }
    }
    #pragma unroll
    for (int mf = 0; mf < 2; ++mf) {
        int mm = m0 + wv * 32 + mf * 16 + (lane & 15);
        if (which == 0) {
            f4v hilo;
            #pragma unroll
            for (int c = 0; c < 4; ++c)
                hilo[c] = acc[mf][c] + __shfl_xor(acc[mf][c], 32);   // n (hi) + n+8 (lo)
            if (lane < 32) {
                int nb = (lane >> 4) * 4;
                u4v hs, ls;
                float ss = 0.f;
                #pragma unroll
                for (int c = 0; c < 4; ++c) {
                    float v = hilo[c] + eb3[nb + c];
                    unsigned short h = f2bf(v);
                    hs[c] = h;
                    ls[c] = f2bf(v - bf2f(h));
                    ss += v * v;
                }
                *(u4v*)(xeH + (size_t)mm * 8 + nb) = hs;
                *(u4v*)(xeL + (size_t)mm * 8 + nb) = ls;
                ss += __shfl_xor(ss, 16);      // combine ch 0-3 with 4-7
                if (lane < 16) splane[mm] = ss;
            }
        } else {
            if ((lane >> 4) == 0)
                ltm[mm] = acc[mf][0] + acc[mf][1] + tb3[0];          // n0 hi + n1 lo
        }
    }
}

// ---------- gram (blocks <620) + ynt (blocks >=620), one launch ----------
__global__ __launch_bounds__(256) void gram_ynt_k(const unsigned short* __restrict__ xeH,
                                                  const unsigned short* __restrict__ xeL,
                                                  const float* __restrict__ splane,
                                                  const float* __restrict__ ltm,
                                                  float* __restrict__ dotsC,
                                                  float* __restrict__ yn,
                                                  float* __restrict__ tempv) {
    if (blockIdx.x >= GRAMBLKS) {    // ynt path: wave per site
        int wv = threadIdx.x >> 6, lane = threadIdx.x & 63;
        int wid = (blockIdx.x - GRAMBLKS) * 4 + wv;
        if (wid >= SITES) return;
        int b = wid / NSITE; int ij = wid % NSITE;
        int i1 = ij / N2, i2 = ij % N2;
        float s1 = 0.f, s2 = 0.f;
        for (int p = lane; p < 100; p += 64) {
            int rr = p / 10, q = p % 10;
            int idx = b * NPIX + (i1 * STR + rr) * WW + i2 * STR + q;
            s1 += splane[idx];
            s2 += ltm[idx];
        }
        #pragma unroll
        for (int o = 32; o; o >>= 1) { s1 += __shfl_xor(s1, o); s2 += __shfl_xor(s2, o); }
        if (lane == 0) {
            yn[wid] = s1;
            tempv[wid] = expf(s2 * (1.f / 100.f));
        }
        return;
    }
    __shared__ unsigned short AsH[32 * GP], AsL[32 * GP];
    __shared__ unsigned short BsH[256 * GP], BsL[256 * GP];
    int blk = blockIdx.x;                  // ((b*31+i1)*2+nh)*KSPLIT + kc
    int kc = blk % KSPLIT; int r = blk / KSPLIT;
    int nh = r & 1; r >>= 1;
    int b = r / N1, i1 = r % N1;
    int b1 = min(max(i1 - 7, 0), 16);
    int t = threadIdx.x;
    int wv = t >> 6, lane = t & 63;
    f4v acc[2][4];
    #pragma unroll
    for (int mt = 0; mt < 2; ++mt)
        #pragma unroll
        for (int nt = 0; nt < 4; ++nt) { f4v z = {0.f,0.f,0.f,0.f}; acc[mt][nt] = z; }
    const size_t pbase = (size_t)b * NPIX;
    for (int ks = kc * 5; ks < kc * 5 + 5; ++ks) {
        __syncthreads();
        {   // stage A: rows = i2 (0..31), pixel p = ks*4+seg
            int idx = t & 127;
            int row = idx >> 2, seg = idx & 3;
            int p = ks * 4 + seg;
            int rr = p / 10, q = p - rr * 10;
            u8v v;
            #pragma unroll
            for (int u = 0; u < 8; ++u) v[u] = 0;
            if (row < 31) {
                size_t a = (pbase + (size_t)(i1 * STR + rr) * WW + row * STR + q) * 8;
                v = *(const u8v*)((t < 128 ? xeH : xeL) + a);
            }
            *(u8v*)((t < 128 ? AsH : AsL) + row * GP + seg * 8) = v;
        }
        #pragma unroll
        for (int rep = 0; rep < 8; ++rep) {   // stage B: rows = dj,j2
            int idx = t + rep * 256;
            int isH = idx < 1024;
            int id2 = idx & 1023;
            int row = id2 >> 2, seg = id2 & 3;
            int dj = nh * 8 + (row >> 5), j2 = row & 31;
            int p = ks * 4 + seg;
            int rr = p / 10, q = p - rr * 10;
            u8v v;
            #pragma unroll
            for (int u = 0; u < 8; ++u) v[u] = 0;
            if (dj < 15 && j2 < 31) {
                size_t a = (pbase + (size_t)((b1 + dj) * STR + rr) * WW + j2 * STR + q) * 8;
                v = *(const u8v*)((isH ? xeH : xeL) + a);
            }
            *(u8v*)((isH ? BsH : BsL) + row * GP + seg * 8) = v;
        }
        __syncthreads();
        s8v afH[2], afL[2], bfH[4], bfL[4];
        #pragma unroll
        for (int mt = 0; mt < 2; ++mt) {
            int ar = mt * 16 + (lane & 15);
            afH[mt] = *(const s8v*)((const short*)AsH + ar * GP + (lane >> 4) * 8);
            afL[mt] = *(const s8v*)((const short*)AsL + ar * GP + (lane >> 4) * 8);
        }
        #pragma unroll
        for (int nt = 0; nt < 4; ++nt) {
            int br = wv * 64 + nt * 16 + (lane & 15);
            bfH[nt] = *(const s8v*)((const short*)BsH + br * GP + (lane >> 4) * 8);
            bfL[nt] = *(const s8v*)((const short*)BsL + br * GP + (lane >> 4) * 8);
        }
        #pragma unroll
        for (int mt = 0; mt < 2; ++mt)
            #pragma unroll
            for (int nt = 0; nt < 4; ++nt) {
                acc[mt][nt] = __builtin_amdgcn_mfma_f32_16x16x32_bf16(afH[mt], bfH[nt], acc[mt][nt], 0, 0, 0);
                acc[mt][nt] = __builtin_amdgcn_mfma_f32_16x16x32_bf16(afH[mt], bfL[nt], acc[mt][nt], 0, 0, 0);
                acc[mt][nt] = __builtin_amdgcn_mfma_f32_16x16x32_bf16(afL[mt], bfH[nt], acc[mt][nt], 0, 0, 0);
            }
    }
    float* dk = dotsC + (size_t)kc * SITES * NOFF;
    #pragma unroll
    for (int mt = 0; mt < 2; ++mt) {
        int i2b = mt * 16 + (lane >> 4) * 4;
        #pragma unroll
        for (int nt = 0; nt < 4; ++nt) {
            int n = wv * 64 + nt * 16 + (lane & 15);
            int dj = nh * 8 + (n >> 5), j2 = n & 31;
            if (dj >= 15 || j2 >= 31) continue;
            #pragma unroll
            for (int c = 0; c < 4; ++c) {
                int i2 = i2b + c;
                if (i2 >= 31) continue;
                int b2 = min(max(i2 - 7, 0), 16);
                int dc = j2 - b2;
                if (dc < 0 || dc >= SWIN) continue;
                size_t site = (size_t)((b * N1 + i1) * N2 + i2);
                dk[site * NOFF + dj * SWIN + dc] = acc[mt][nt][c];
            }
        }
    }
}

// ---------- fused softmax + A-build: wave per site writes Aglob rows directly ----------
__global__ __launch_bounds__(256) void softmax_awrite_k(const float* __restrict__ dotsC,
                                                        const float* __restrict__ yn,
                                                        const float* __restrict__ tempv,
                                                        unsigned short* __restrict__ Aglob) {
    __shared__ float sw[4][228];
    int wv = threadIdx.x >> 6, lane = threadIdx.x & 63;
    int wid = blockIdx.x * 4 + wv;
    bool active = (wid < SITES);
    int wids = active ? wid : (SITES - 1);
    int b = wids / NSITE; int ij = wids % NSITE;
    int i1 = ij / N2, i2 = ij % N2;
    int b1 = min(max(i1 - 7, 0), 16);
    int b2 = min(max(i2 - 7, 0), 16);
    int pglob = i2 >> 1, s = i2 & 1;
    unsigned short* Abase = Aglob + (size_t)((b * N1 + i1) * 256) * KP;
    float yns = yn[wids];
    float tvi = 1.f / tempv[wids];
    float lg[4];
    #pragma unroll
    for (int r = 0; r < 4; ++r) {
        int t = lane + 64 * r;
        lg[r] = -1e9f;
        if (t < NOFF) {
            float dot = 0.f;
            #pragma unroll
            for (int kc = 0; kc < KSPLIT; ++kc)
                dot += dotsC[((size_t)kc * SITES + wids) * NOFF + t];
            int dj = t / SWIN, dc = t % SWIN;
            int j1 = b1 + dj, j2 = b2 + dc;
            float xn = yn[(b * N1 + j1) * N2 + j2];
            float d = yns + xn - 2.f * dot;
            lg[r] = -d * tvi;
            if (j1 == i1 && j2 == i2) lg[r] = -1e9f;
        }
    }
    for (int k = 0; k < KK; ++k) {
        float m = fmaxf(fmaxf(lg[0], lg[1]), fmaxf(lg[2], lg[3]));
        #pragma unroll
        for (int o = 32; o; o >>= 1) m = fmaxf(m, __shfl_xor(m, o));
        float ex[4]; float ssum = 0.f;
        #pragma unroll
        for (int r = 0; r < 4; ++r) { ex[r] = __expf(lg[r] - m); ssum += ex[r]; }
        #pragma unroll
        for (int o = 32; o; o >>= 1) ssum += __shfl_xor(ssum, o);
        float inv = 1.f / ssum;
        #pragma unroll
        for (int r = 0; r < 4; ++r) {
            float wgt = ex[r] * inv;
            int t = lane + 64 * r;
            if (t < NOFF) sw[wv][t] = wgt;
            lg[r] += log1pf(-fminf(wgt, 1.f - 1e-6f));
        }
        __syncthreads();
        if (active && lane < 60) {
            u8v o;
            #pragma unroll
            for (int u = 0; u < 8; ++u) {
                int n = lane * 8 + u;
                int dj = n >> 5, j2 = n & 31;
                int dc = j2 - b2;
                o[u] = (j2 < 31 && dc >= 0 && dc < SWIN) ? f2bf(sw[wv][dj * SWIN + dc]) : (unsigned short)0;
            }
            int m_ = 16 * pglob + k + 7 * s;
            *(u8v*)(Abase + (size_t)m_ * KP + lane * 8) = o;
        }
        __syncthreads();
    }
    if (active && s == 0 && lane < 60) {
        u8v z;
        #pragma unroll
        for (int u = 0; u < 8; ++u) z[u] = 0;
        *(u8v*)(Abase + (size_t)(16 * pglob + 14) * KP + lane * 8) = z;
        *(u8v*)(Abase + (size_t)(16 * pglob + 15) * KP + lane * 8) = z;
        if (i2 == 30) {
            #pragma unroll
            for (int sl = 7; sl < 14; ++sl)
                *(u8v*)(Abase + (size_t)(16 * 15 + sl) * KP + lane * 8) = z;
        }
    }
}

// ---------- agg GEMM: per (b,i1): C[256 m][800 e] = A[256x480] * ypT-slice^T ----------
__global__ __launch_bounds__(256) void agg_gemm_k(const unsigned short* __restrict__ Aglob,
                                                  const unsigned short* __restrict__ ypT,
                                                  unsigned short* __restrict__ zbuf) {
    __shared__ unsigned short As[128 * 40];
    __shared__ unsigned short Bs[160 * 40];
    int blk = blockIdx.x;                     // b*310 + i1*10 + mh*5 + nc
    int b = blk / 310; int r = blk % 310;
    int i1 = r / 10; int r2 = r % 10;
    int mh = r2 / 5, nc = r2 % 5;
    int b1 = min(max(i1 - 7, 0), 16);
    int t = threadIdx.x;
    int wv = t >> 6, lane = t & 63;
    int wm = (wv & 1) * 64, we = (wv >> 1) * 80;
    const unsigned short* Ab = Aglob + ((size_t)(b * N1 + i1) * 256 + mh * 128) * KP;
    const unsigned short* Bb = ypT + ((size_t)b * 800 + nc * 160) * COLP + b1 * 32;
    f4v accr[4][5];
    #pragma unroll
    for (int mt = 0; mt < 4; ++mt)
        #pragma unroll
        for (int et = 0; et < 5; ++et) { f4v z = {0.f,0.f,0.f,0.f}; accr[mt][et] = z; }
    for (int ks = 0; ks < 15; ++ks) {
        __syncthreads();
        #pragma unroll
        for (int it = 0; it < 2; ++it) {
            int idx = t + it * 256;
            int row = idx >> 2, seg = idx & 3;
            *(u8v*)(As + row * 40 + seg * 8) = *(const u8v*)(Ab + (size_t)row * KP + ks * 32 + seg * 8);
        }
        #pragma unroll
        for (int it = 0; it < 3; ++it) {
            int idx = t + it * 256;
            if (idx < 640) {
                int row = idx >> 2, seg = idx & 3;
                *(u8v*)(Bs + row * 40 + seg * 8) = *(const u8v*)(Bb + (size_t)row * COLP + ks * 32 + seg * 8);
            }
        }
        __syncthreads();
        s8v af[4], bf[5];
        #pragma unroll
        for (int mt = 0; mt < 4; ++mt)
            af[mt] = *(const s8v*)((const short*)As + (wm + mt * 16 + (lane & 15)) * 40 + (lane >> 4) * 8);
        #pragma unroll
        for (int et = 0; et < 5; ++et)
            bf[et] = *(const s8v*)((const short*)Bs + (we + et * 16 + (lane & 15)) * 40 + (lane >> 4) * 8);
        #pragma unroll
        for (int mt = 0; mt < 4; ++mt)
            #pragma unroll
            for (int et = 0; et < 5; ++et)
                accr[mt][et] = __builtin_amdgcn_mfma_f32_16x16x32_bf16(af[mt], bf[et], accr[mt][et], 0, 0, 0);
    }
    unsigned short* zb = zbuf + ((size_t)(b * N1 + i1) * 256 + mh * 128) * 800 + nc * 160;
    #pragma unroll
    for (int mt = 0; mt < 4; ++mt) {
        int mrow = wm + mt * 16 + (lane >> 4) * 4;
        #pragma unroll
        for (int et = 0; et < 5; ++et) {
            int ecol = we + et * 16 + (lane & 15);
            #pragma unroll
            for (int c = 0; c < 4; ++c)
                zb[(size_t)(mrow + c) * 800 + ecol] = f2bf(accr[mt][et][c]);
        }
    }
}

// ---------- finalize: thread per (b,pixel), all 64 channels ----------
__global__ __launch_bounds__(256) void finalize_k(const unsigned short* __restrict__ zbuf,
                                                  const float* __restrict__ xd,
                                                  float* __restrict__ out) {
    int pid = blockIdx.x * 256 + threadIdx.x;      // b*NPIX + pix
    if (pid >= BN * NPIX) return;
    int b = pid / NPIX, pix = pid % NPIX;
    int h = pix / WW, w_ = pix % WW;
    int lo1 = max(0, (h - 5) / 5),  hi1 = min(30, h / 5);
    int lo2 = max(0, (w_ - 5) / 5), hi2 = min(30, w_ / 5);
    float cntinv = 1.f / (float)((hi1 - lo1 + 1) * (hi2 - lo2 + 1));
    float xv[8];
    #pragma unroll
    for (int cd = 0; cd < 8; ++cd) {
        xv[cd] = xd[((size_t)(b * 8 + cd)) * NPIX + pix];
        out[((size_t)(b * 64 + cd)) * NPIX + pix] = xv[cd];
    }
    for (int k = 0; k < KK; ++k) {
        float s[8];
        #pragma unroll
        for (int cd = 0; cd < 8; ++cd) s[cd] = 0.f;
        for (int i1 = lo1; i1 <= hi1; ++i1) {
            int pi = h - 5 * i1;
            for (int i2 = lo2; i2 <= hi2; ++i2) {
                int pj = w_ - 5 * i2;
                int m = 16 * (i2 >> 1) + k + 7 * (i2 & 1);
                const unsigned short* zp = zbuf + ((size_t)(b * N1 + i1) * 256 + m) * 800 + (pi * 10 + pj) * 8;
                u8v zv = *(const u8v*)zp;
                #pragma unroll
                for (int cd = 0; cd < 8; ++cd) s[cd] += bf2f(zv[cd]);
            }
        }
        #pragma unroll
        for (int cd = 0; cd < 8; ++cd)
            out[((size_t)(b * 64 + (k + 1) * 8 + cd)) * NPIX + pix] = s[cd] * cntinv - xv[cd];
    }
}

extern "C" void kernel_launch(void* const* d_in, const int* in_sizes, int n_in,
                              void* d_out, int out_size, void* d_ws, size_t ws_size,
                              hipStream_t stream) {
    (void)in_sizes; (void)n_in; (void)out_size; (void)ws_size;
    const float* x_data = (const float*)d_in[0];
    const float* x_faet = (const float*)d_in[1];
    const float* ew1 = (const float*)d_in[2];  const float* eb1 = (const float*)d_in[3];
    const float* ew2 = (const float*)d_in[4];  const float* eb2 = (const float*)d_in[5];
    const float* ew3 = (const float*)d_in[6];  const float* eb3 = (const float*)d_in[7];
    const float* tw1 = (const float*)d_in[8];  const float* tb1 = (const float*)d_in[9];
    const float* tw2 = (const float*)d_in[10]; const float* tb2 = (const float*)d_in[11];
    const float* tw3 = (const float*)d_in[12]; const float* tb3 = (const float*)d_in[13];
    float* out = (float*)d_out;

    // workspace layout (bytes), total 44.8 MB (same as R11):
    char* base = (char*)d_ws;
    unsigned short* h1 = (unsigned short*)(base);
    unsigned short* h2 = (unsigned short*)(base + 13107200);
    unsigned short* wp1 = (unsigned short*)(base + 13107200);   // dead before conv2 writes h2
    unsigned short* wp = (unsigned short*)(base + 26214400);
    float* yn    = (float*)(base + 26361856);
    float* tempv = (float*)(base + 26370048);
    unsigned short* ypT = (unsigned short*)(base + 26378240);
    unsigned short* xeH = (unsigned short*)(base + 29552640);
    unsigned short* xeL = (unsigned short*)(base + 30371840);
    float* ltm    = (float*)(base + 31191040);
    float* splane = (float*)(base + 31395840);
    unsigned short* wp3 = (unsigned short*)(base + 37546240);
    unsigned short* Aglob = (unsigned short*)(base + 29552640);
    float* dotsC = (float*)h2;
    unsigned short* zbuf = (unsigned short*)base;

    prep_k<<<408, 256, 0, stream>>>(ew2, tw2, ew1, tw1, ew3, tw3, wp, wp1, wp3);
    conv1_ypt_k<<<800 + 1600, 256, 0, stream>>>(x_faet, x_data, wp1, eb1, tb1, h1, ypT);
    conv2_mfma_k<<<dim3(400, 2), 256, 0, stream>>>(h1, wp, eb2, tb2, h2);
    conv3_mfma_k<<<dim3(400, 2), 256, 0, stream>>>(h2, wp3, eb3, tb3, xeH, xeL, splane, ltm);

    gram_ynt_k<<<GRAMBLKS + YNTBLKS, 256, 0, stream>>>(xeH, xeL, splane, ltm, dotsC, yn, tempv);
    softmax_awrite_k<<<YNTBLKS, 256, 0, stream>>>(dotsC, yn, tempv, Aglob);

    agg_gemm_k<<<BN * 310, 256, 0, stream>>>(Aglob, ypT, zbuf);
    finalize_k<<<(BN * NPIX + 255) / 256, 256, 0, stream>>>(zbuf, x_data, out);
}